// Round 2
// baseline (1846.286 us; speedup 1.0000x reference)
//
#include <hip/hip_runtime.h>
#include <cstdint>

#define BB 4
#define CC 48
#define HW 16384
#define D1 384
#define HEADS 8

typedef unsigned short ushort_t;

__device__ __forceinline__ float bf2f(ushort_t u){
  union{uint32_t i; float f;} v; v.i = ((uint32_t)u)<<16; return v.f;
}
__device__ __forceinline__ ushort_t f2bf(float f){
  union{float f; uint32_t i;} v; v.f=f;
  uint32_t x = v.i;
  uint32_t r = (x + 0x7fff + ((x>>16)&1)) >> 16;
  return (ushort_t)r;
}

__global__ __launch_bounds__(256) void k_zero(float* p, int n){
  int i = blockIdx.x*256 + threadIdx.x;
  if(i<n) p[i]=0.f;
}

// 9 boundary stats per (b, x-channel): T, row0, row127, col0, col127, 4 corners
__global__ __launch_bounds__(256) void k_xstats(const float* __restrict__ x,
                                                float* __restrict__ xst){
  int ch = blockIdx.x, b = blockIdx.y;
  const float* p = x + ((size_t)b*CC + ch)*HW;
  int tid = threadIdx.x;
  float T=0,R0=0,R1=0,C0=0,C1=0;
  for(int i=tid;i<HW;i+=256){
    float v = p[i];
    T += v;
    if(i<128)      R0 += v;
    if(i>=16256)   R1 += v;
    int xc = i & 127;
    if(xc==0)      C0 += v;
    if(xc==127)    C1 += v;
  }
  __shared__ float red[20];
  for(int off=32;off;off>>=1){
    T  += __shfl_down(T,off);  R0 += __shfl_down(R0,off); R1 += __shfl_down(R1,off);
    C0 += __shfl_down(C0,off); C1 += __shfl_down(C1,off);
  }
  int wv = tid>>6, ln = tid&63;
  if(ln==0){ red[wv]=T; red[4+wv]=R0; red[8+wv]=R1; red[12+wv]=C0; red[16+wv]=C1; }
  __syncthreads();
  if(tid==0){
    float* o = xst + ((size_t)b*CC + ch)*9;
    o[0]=red[0]+red[1]+red[2]+red[3];
    o[1]=red[4]+red[5]+red[6]+red[7];
    o[2]=red[8]+red[9]+red[10]+red[11];
    o[3]=red[12]+red[13]+red[14]+red[15];
    o[4]=red[16]+red[17]+red[18]+red[19];
    o[5]=p[0]; o[6]=p[127]; o[7]=p[16256]; o[8]=p[16383];
  }
}

// fused 1x1 conv + grouped 3x3 dwconv for q,k,v channels (0..1151), bf16 out.
// Also accumulates q/k norm^2 (qn2 buffer; kn2 = qn2+1536).
__global__ __launch_bounds__(256,2) void k_conv(const float* __restrict__ x,
                                                const float* __restrict__ qw,
                                                const float* __restrict__ dw,
                                                ushort_t* __restrict__ qkvd,
                                                float* __restrict__ qn2){
  __shared__ ushort_t xs[48][328];   // bf16 x halo, 18x18=324 per channel
  __shared__ float pre[32][326];     // fp32 1x1 output halo tile
  int tid  = threadIdx.x;
  int tile = blockIdx.x;             // 64 tiles of 16x16
  int cb   = blockIdx.y*32;          // out-channel base (0..1151)
  int b    = blockIdx.z;
  int ty0 = (tile>>3)<<4, tx0 = (tile&7)<<4;
  // phase 1: x halo -> LDS (bf16)
  const float* xb = x + (size_t)b*CC*HW;
  for(int idx=tid; idx<48*324; idx+=256){
    int ch = idx/324, rem = idx - ch*324;
    int iy = rem/18, ix = rem - iy*18;
    int gy = ty0+iy-1, gx = tx0+ix-1;
    float v = 0.f;
    if((unsigned)gy<128u && (unsigned)gx<128u) v = xb[(size_t)ch*HW + gy*128 + gx];
    xs[ch][rem] = f2bf(v);
  }
  __syncthreads();
  // phase 2: 1x1 conv over the halo: pre[o][p], o in 0..31, p in 0..323
  {
    float xr0[48], xr1[48];
    int p0 = tid, p1 = tid+256;
    bool has1 = (p1 < 324);
    int p1c = has1 ? p1 : 0;
    #pragma unroll
    for(int c=0;c<48;c++) xr0[c] = bf2f(xs[c][p0]);
    #pragma unroll
    for(int c=0;c<48;c++) xr1[c] = bf2f(xs[c][p1c]);
    #pragma unroll 4
    for(int o=0;o<32;o++){
      const float* w = qw + (size_t)(cb+o)*48;  // uniform -> scalar loads
      float s0=0.f, s1=0.f;
      #pragma unroll
      for(int c=0;c<48;c++){ float wv=w[c]; s0 += wv*xr0[c]; s1 += wv*xr1[c]; }
      pre[o][p0] = s0;
      if(has1) pre[o][p1] = s1;
    }
  }
  __syncthreads();
  // phase 3: depthwise 3x3 (4 groups of 8ch)
  int y = tid>>4, xx = tid&15;
  float acc[32];
  #pragma unroll
  for(int i=0;i<32;i++) acc[i]=0.f;
  #pragma unroll
  for(int g=0;g<4;g++){
    #pragma unroll
    for(int dy=0;dy<3;dy++){
      #pragma unroll
      for(int dx=0;dx<3;dx++){
        float iv[8];
        #pragma unroll
        for(int i=0;i<8;i++) iv[i] = pre[g*8+i][(y+dy)*18 + xx+dx];
        #pragma unroll
        for(int oc=0;oc<8;oc++){
          const float* wp = dw + (size_t)(cb+g*8+oc)*72 + dy*3 + dx;  // uniform
          float s = acc[g*8+oc];
          #pragma unroll
          for(int i=0;i<8;i++) s += wp[i*9]*iv[i];
          acc[g*8+oc] = s;
        }
      }
    }
  }
  int pos = (ty0+y)*128 + tx0+xx;
  ushort_t* dst = qkvd + ((size_t)b*1152 + cb)*HW + pos;
  #pragma unroll
  for(int o=0;o<32;o++) dst[(size_t)o*HW] = f2bf(acc[o]);
  // norm^2 accumulation for q (cb<384) and k (384<=cb<768)
  if(cb < 768){
    size_t nbase = (cb<384) ? ((size_t)b*D1 + cb) : ((size_t)1536 + b*D1 + (cb-384));
    #pragma unroll
    for(int o=0;o<32;o++){
      float v = acc[o]*acc[o];
      for(int off=32; off; off>>=1) v += __shfl_down(v, off);
      if((tid&63)==0) atomicAdd(qn2 + nbase + o, v);
    }
  }
}

// partial S per block: Spart[b][h][blk][c*48+d] = sum over 512 positions of q_c*k_d
__global__ __launch_bounds__(256) void k_S(const ushort_t* __restrict__ qkvd,
                                           float* __restrict__ Spart){
  __shared__ float qk[96][132];   // 50688 B
  int tid = threadIdx.x;
  int blk = blockIdx.x;           // 32 per (b,h), each 4 chunks of 128 pos
  int h = blockIdx.y, b = blockIdx.z;
  int wave = tid>>6, lane = tid&63;
  int ci0 = (lane>>3)*6, di0 = (lane&7)*6;
  float sacc[6][6];
  #pragma unroll
  for(int i=0;i<6;i++)
    #pragma unroll
    for(int j=0;j<6;j++) sacc[i][j]=0.f;
  const ushort_t* qb = qkvd + ((size_t)b*1152 + h*48)*HW;
  const ushort_t* kb = qb + (size_t)384*HW;
  for(int chunk=0;chunk<4;chunk++){
    int p0 = (blk*4+chunk)*128;
    __syncthreads();
    #pragma unroll 4
    for(int it=0; it<24; it++){
      int e = tid + it*256;            // 96 rows x 64 ushort2
      int ch = e>>6, cc = (e&63)*2;
      const ushort_t* src = (ch<48) ? (qb + (size_t)ch*HW) : (kb + (size_t)(ch-48)*HW);
      uint32_t u = *(const uint32_t*)(src + p0 + cc);
      qk[ch][cc]   = bf2f((ushort_t)(u & 0xffff));
      qk[ch][cc+1] = bf2f((ushort_t)(u >> 16));
    }
    __syncthreads();
    int pb = wave*32;
    #pragma unroll 2
    for(int pp=0; pp<32; pp+=2){
      int p = pb+pp;
      float2 qv[6], kv[6];
      #pragma unroll
      for(int i=0;i<6;i++) qv[i] = *(const float2*)&qk[ci0+i][p];
      #pragma unroll
      for(int j=0;j<6;j++) kv[j] = *(const float2*)&qk[48+di0+j][p];
      #pragma unroll
      for(int i=0;i<6;i++)
        #pragma unroll
        for(int j=0;j<6;j++){
          sacc[i][j] += qv[i].x*kv[j].x;
          sacc[i][j] += qv[i].y*kv[j].y;
        }
    }
  }
  __syncthreads();
  float* scr = &qk[0][0];   // reuse LDS: 4*2304 = 9216 floats <= 12672
  #pragma unroll
  for(int i=0;i<6;i++)
    #pragma unroll
    for(int j=0;j<6;j++)
      scr[wave*2304 + (ci0+i)*48 + di0+j] = sacc[i][j];
  __syncthreads();
  float* outp = Spart + ((size_t)((b*HEADS+h)*32 + blk))*2304;
  for(int idx=tid; idx<2304; idx+=256){
    outp[idx] = scr[idx] + scr[2304+idx] + scr[4608+idx] + scr[6912+idx];
  }
}

// per b: l-stats from x-stats -> dwconv-mean -> fc1 -> relu -> fc2 -> swish -> constv = po1@L
__global__ __launch_bounds__(384) void k_mlp(const float* __restrict__ xst,
                                             const float* __restrict__ qw,
                                             const float* __restrict__ dw,
                                             const float* __restrict__ fc1w,
                                             const float* __restrict__ fc1b,
                                             const float* __restrict__ fc2w,
                                             const float* __restrict__ fc2b,
                                             const float* __restrict__ po1,
                                             float* __restrict__ constv){
  int b = blockIdx.x, tid = threadIdx.x;
  __shared__ float xsl[432];
  __shared__ float lst[3456];   // 384 l-channels x 9 stats
  __shared__ float avg[384];
  __shared__ float y1[24];
  __shared__ float Lb[384];
  for(int i=tid;i<432;i+=384) xsl[i] = xst[(size_t)b*432 + i];
  __syncthreads();
  {
    float st[9];
    #pragma unroll
    for(int s=0;s<9;s++) st[s]=0.f;
    const float* w = qw + (size_t)(1152+tid)*48;
    for(int c=0;c<48;c++){
      float wv = w[c];
      #pragma unroll
      for(int s=0;s<9;s++) st[s] += wv*xsl[c*9+s];
    }
    #pragma unroll
    for(int s=0;s<9;s++) lst[tid*9+s] = st[s];
  }
  __syncthreads();
  {
    int base = tid & ~7;
    const float* ls = &lst[base*9];
    float s = 0.f;
    #pragma unroll
    for(int i=0;i<8;i++){
      float T=ls[i*9+0],R0=ls[i*9+1],R1=ls[i*9+2],C0=ls[i*9+3],C1=ls[i*9+4];
      float c00=ls[i*9+5],c0W=ls[i*9+6],cH0=ls[i*9+7],cHW=ls[i*9+8];
      const float* wp = dw + (size_t)(1152+tid)*72 + i*9;
      #pragma unroll
      for(int dy=0;dy<3;dy++){
        float rm = (dy==0)?R1:((dy==2)?R0:0.f);
        #pragma unroll
        for(int dx=0;dx<3;dx++){
          float cm = (dx==0)?C1:((dx==2)?C0:0.f);
          float corner = 0.f;
          if(dy==0&&dx==0)corner=cHW;
          if(dy==0&&dx==2)corner=cH0;
          if(dy==2&&dx==0)corner=c0W;
          if(dy==2&&dx==2)corner=c00;
          s += wp[dy*3+dx]*(T-rm-cm+corner);
        }
      }
    }
    avg[tid] = s*(1.f/16384.f);
  }
  __syncthreads();
  if(tid<24){
    float s = fc1b[tid];
    const float* w = fc1w + (size_t)tid*384;
    for(int c=0;c<384;c++) s += w[c]*avg[c];
    y1[tid] = fmaxf(s,0.f);
  }
  __syncthreads();
  {
    float s = fc2b[tid];
    const float* w = fc2w + (size_t)tid*24;
    #pragma unroll
    for(int j=0;j<24;j++) s += w[j]*y1[j];
    Lb[tid] = s/(1.f+__expf(-s));
  }
  __syncthreads();
  if(tid<48){
    const float* w = po1 + (size_t)tid*384;
    float s = 0.f;
    for(int c=0;c<384;c++) s += w[c]*Lb[c];
    constv[b*48+tid] = s;
  }
}

// per (b,h): sum Spart, normalize, softmax, m2t[b][h*48+d][o] = sum_c po1[o][h*48+c]*attn[c][d]
__global__ __launch_bounds__(256) void k_attn(const float* __restrict__ Spart,
                                              const float* __restrict__ qn2,
                                              const float* __restrict__ temp,
                                              const float* __restrict__ po1,
                                              float* __restrict__ m2t){
  int h = blockIdx.x, b = blockIdx.y, tid = threadIdx.x;
  __shared__ float att[2304];
  __shared__ float nq[48], nk[48];
  const float* kn2 = qn2 + 1536;
  if(tid<48)      nq[tid]    = fmaxf(sqrtf(qn2[(size_t)b*D1 + h*48 + tid]),    1e-12f);
  else if(tid<96) nk[tid-48] = fmaxf(sqrtf(kn2[(size_t)b*D1 + h*48 + tid-48]), 1e-12f);
  __syncthreads();
  float tmp = temp[h];
  const float* Sp = Spart + ((size_t)(b*HEADS+h)*32)*2304;
  for(int idx=tid; idx<2304; idx+=256){
    float s = 0.f;
    for(int blk=0;blk<32;blk++) s += Sp[(size_t)blk*2304 + idx];
    int c = idx/48, d = idx - c*48;
    att[idx] = s*tmp/(nq[c]*nk[d]);
  }
  __syncthreads();
  if(tid<48){
    float* row = &att[tid*48];
    float m = -1e30f;
    for(int d=0;d<48;d++) m = fmaxf(m,row[d]);
    float s = 0.f;
    for(int d=0;d<48;d++){ float e=__expf(row[d]-m); row[d]=e; s+=e; }
    float inv = 1.f/s;
    for(int d=0;d<48;d++) row[d]*=inv;
  }
  __syncthreads();
  for(int idx=tid; idx<2304; idx+=256){
    int d = idx/48, o = idx - d*48;
    float s = 0.f;
    for(int c=0;c<48;c++) s += po1[(size_t)o*D1 + h*48 + c]*att[c*48+d];
    m2t[((size_t)b*D1 + h*48 + d)*48 + o] = s;
  }
}

// out[b][o][pos] = x + constv[o] + sum_hd m2t[b][hd][o]*v[b][hd][pos]
__global__ __launch_bounds__(256) void k_final(const ushort_t* __restrict__ qkvd,
                                               const float* __restrict__ m2t,
                                               const float* __restrict__ constv,
                                               const float* __restrict__ x,
                                               float* __restrict__ out){
  int tid = threadIdx.x;
  int pos = blockIdx.x*256 + tid;
  int b   = blockIdx.y;
  const ushort_t* vbase = qkvd + ((size_t)b*1152 + 768)*HW + pos;
  const float* m2 = m2t + (size_t)b*D1*48;
  float acc[48];
  #pragma unroll
  for(int o=0;o<48;o++) acc[o]=0.f;
  for(int ch=0;ch<384;ch+=8){
    float vv[8];
    #pragma unroll
    for(int j=0;j<8;j++) vv[j] = bf2f(vbase[(size_t)(ch+j)*HW]);
    #pragma unroll
    for(int j=0;j<8;j++){
      const float* mrow = m2 + (size_t)(ch+j)*48;   // uniform -> scalar loads
      #pragma unroll
      for(int o=0;o<48;o++) acc[o] += mrow[o]*vv[j];
    }
  }
  const float* xb = x   + (size_t)b*CC*HW + pos;
  float*       ob = out + (size_t)b*CC*HW + pos;
  const float* cv = constv + b*48;
  #pragma unroll
  for(int o=0;o<48;o++) ob[(size_t)o*HW] = xb[(size_t)o*HW] + cv[o] + acc[o];
}

extern "C" void kernel_launch(void* const* d_in, const int* in_sizes, int n_in,
                              void* d_out, int out_size, void* d_ws, size_t ws_size,
                              hipStream_t stream){
  const float* x    = (const float*)d_in[0];
  const float* qw   = (const float*)d_in[1];
  const float* dw   = (const float*)d_in[2];
  const float* po1  = (const float*)d_in[3];
  const float* fc1w = (const float*)d_in[4];
  const float* fc1b = (const float*)d_in[5];
  const float* fc2w = (const float*)d_in[6];
  const float* fc2b = (const float*)d_in[7];
  const float* temp = (const float*)d_in[8];
  float* out = (float*)d_out;
  char* ws = (char*)d_ws;

  // workspace layout (total ~160.75 MB)
  ushort_t* qkvd   = (ushort_t*)(ws);                 // 4*1152*16384*2 = 150,994,944
  float*    Spart  = (float*)(ws + 150994944);        // 4*8*32*2304*4 = 9,437,184
  float*    qn2    = (float*)(ws + 160432128);        // 6144 (kn2 = qn2+1536 floats)
  float*    xst    = (float*)(ws + 160444416);        // 4*48*9*4 = 6912
  float*    constv = (float*)(ws + 160451328);        // 768
  float*    m2t    = (float*)(ws + 160452096);        // 294912

  k_zero  <<<dim3(12),           256, 0, stream>>>(qn2, 3072);
  k_xstats<<<dim3(48,BB),        256, 0, stream>>>(x, xst);
  k_conv  <<<dim3(64,36,BB),     256, 0, stream>>>(x, qw, dw, qkvd, qn2);
  k_S     <<<dim3(32,HEADS,BB),  256, 0, stream>>>(qkvd, Spart);
  k_mlp   <<<dim3(BB),           384, 0, stream>>>(xst, qw, dw, fc1w, fc1b, fc2w, fc2b, po1, constv);
  k_attn  <<<dim3(HEADS,BB),     256, 0, stream>>>(Spart, qn2, temp, po1, m2t);
  k_final <<<dim3(64,BB),        256, 0, stream>>>(qkvd, m2t, constv, x, out);
}

// Round 3
// 736.767 us; speedup vs baseline: 2.5059x; 2.5059x over previous
//
#include <hip/hip_runtime.h>
#include <cstdint>

#define BB 4
#define CC 48
#define HW 16384
#define D1 384
#define HEADS 8

typedef unsigned short ushort_t;
typedef __attribute__((ext_vector_type(8))) short short8;
typedef __attribute__((ext_vector_type(4))) float f32x4;

__device__ __forceinline__ float bf2f(ushort_t u){
  union{uint32_t i; float f;} v; v.i = ((uint32_t)u)<<16; return v.f;
}
__device__ __forceinline__ ushort_t f2bf(float f){
  union{float f; uint32_t i;} v; v.f=f;
  uint32_t x = v.i;
  uint32_t r = (x + 0x7fff + ((x>>16)&1)) >> 16;
  return (ushort_t)r;
}

__global__ __launch_bounds__(256) void k_zero(float* p, int n){
  int i = blockIdx.x*256 + threadIdx.x;
  if(i<n) p[i]=0.f;
}

// 9 boundary stats per (b, x-channel): T, row0, row127, col0, col127, 4 corners
__global__ __launch_bounds__(256) void k_xstats(const float* __restrict__ x,
                                                float* __restrict__ xst){
  int ch = blockIdx.x, b = blockIdx.y;
  const float* p = x + ((size_t)b*CC + ch)*HW;
  int tid = threadIdx.x;
  float T=0,R0=0,R1=0,C0=0,C1=0;
  for(int i=tid;i<HW;i+=256){
    float v = p[i];
    T += v;
    if(i<128)      R0 += v;
    if(i>=16256)   R1 += v;
    int xc = i & 127;
    if(xc==0)      C0 += v;
    if(xc==127)    C1 += v;
  }
  __shared__ float red[20];
  for(int off=32;off;off>>=1){
    T  += __shfl_down(T,off);  R0 += __shfl_down(R0,off); R1 += __shfl_down(R1,off);
    C0 += __shfl_down(C0,off); C1 += __shfl_down(C1,off);
  }
  int wv = tid>>6, ln = tid&63;
  if(ln==0){ red[wv]=T; red[4+wv]=R0; red[8+wv]=R1; red[12+wv]=C0; red[16+wv]=C1; }
  __syncthreads();
  if(tid==0){
    float* o = xst + ((size_t)b*CC + ch)*9;
    o[0]=red[0]+red[1]+red[2]+red[3];
    o[1]=red[4]+red[5]+red[6]+red[7];
    o[2]=red[8]+red[9]+red[10]+red[11];
    o[3]=red[12]+red[13]+red[14]+red[15];
    o[4]=red[16]+red[17]+red[18]+red[19];
    o[5]=p[0]; o[6]=p[127]; o[7]=p[16256]; o[8]=p[16383];
  }
}

// fused 1x1(MFMA) + grouped 3x3 dwconv for q,k,v channels (0..1151), bf16 out.
// LDS: xs[48][330] bf16 x-halo (pos = iy*18+ix), pre[32][330] bf16 1x1 output.
#define R1L 330
__global__ __launch_bounds__(256,3) void k_conv(const float* __restrict__ x,
                                                const float* __restrict__ qw,
                                                const float* __restrict__ dw,
                                                ushort_t* __restrict__ qkvd){
  __shared__ ushort_t xs[48*R1L];    // 31680 B
  __shared__ ushort_t pre[32*R1L];   // 21120 B
  int tid  = threadIdx.x;
  int tile = blockIdx.x;             // 64 tiles of 16x16
  int cb   = blockIdx.y*32;          // out-channel base (0..1151)
  int b    = blockIdx.z;
  int ty0 = (tile>>3)<<4, tx0 = (tile&7)<<4;

  // ---- phase 1: x halo -> LDS bf16 (vectorized float4 loads) ----
  const float* xb = x + (size_t)b*CC*HW;
  for(int f=tid; f<5184; f+=256){        // 48ch * 18rows * 6 float4-slots
    int unit = f/6, s = f - unit*6;
    int c = unit/18, iy = unit - c*18;
    int gy = ty0 + iy - 1;
    int gx0 = tx0 - 4 + s*4;
    float4 v = make_float4(0.f,0.f,0.f,0.f);
    if((unsigned)gy < 128u && gx0 >= 0 && gx0 < 128)
      v = *(const float4*)(xb + (size_t)c*HW + gy*128 + gx0);
    const float* vp = (const float*)&v;
    #pragma unroll
    for(int k=0;k<4;k++){
      int ix = s*4 + k - 3;
      if(ix >= 0 && ix < 18) xs[c*R1L + iy*18 + ix] = f2bf(vp[k]);
    }
  }
  __syncthreads();

  // ---- phase 2: 1x1 conv via MFMA: pre[oc][p] = sum_c qw[cb+oc][c]*xs[c][p] ----
  {
    int wave = tid>>6, lane = tid&63;
    int mrow = lane&15, quad = lane>>4;
    short8 A[2][2];
    #pragma unroll
    for(int Mt=0;Mt<2;Mt++){
      const float* qr = qw + (size_t)(cb + Mt*16 + mrow)*48;
      float4 f0 = *(const float4*)(qr + quad*8);
      float4 f1 = *(const float4*)(qr + quad*8 + 4);
      const float* p0 = (const float*)&f0; const float* p1 = (const float*)&f1;
      #pragma unroll
      for(int j=0;j<4;j++){ A[Mt][0][j] = (short)f2bf(p0[j]); A[Mt][0][4+j] = (short)f2bf(p1[j]); }
      if(quad<2){
        float4 g0 = *(const float4*)(qr + 32 + quad*8);
        float4 g1 = *(const float4*)(qr + 32 + quad*8 + 4);
        const float* q0 = (const float*)&g0; const float* q1 = (const float*)&g1;
        #pragma unroll
        for(int j=0;j<4;j++){ A[Mt][1][j] = (short)f2bf(q0[j]); A[Mt][1][4+j] = (short)f2bf(q1[j]); }
      } else {
        #pragma unroll
        for(int j=0;j<8;j++) A[Mt][1][j] = 0;
      }
    }
    for(int nt=wave; nt<21; nt+=4){
      int p = nt*16 + mrow;
      short8 B0, B1;
      #pragma unroll
      for(int j=0;j<8;j++){ B0[j]=0; B1[j]=0; }
      if(p < 324){
        #pragma unroll
        for(int j=0;j<8;j++) B0[j] = (short)xs[(quad*8+j)*R1L + p];
        if(quad<2){
          #pragma unroll
          for(int j=0;j<8;j++) B1[j] = (short)xs[(32+quad*8+j)*R1L + p];
        }
      }
      f32x4 acc0 = {0.f,0.f,0.f,0.f}, acc1 = {0.f,0.f,0.f,0.f};
      acc0 = __builtin_amdgcn_mfma_f32_16x16x32_bf16(A[0][0], B0, acc0, 0,0,0);
      acc0 = __builtin_amdgcn_mfma_f32_16x16x32_bf16(A[0][1], B1, acc0, 0,0,0);
      acc1 = __builtin_amdgcn_mfma_f32_16x16x32_bf16(A[1][0], B0, acc1, 0,0,0);
      acc1 = __builtin_amdgcn_mfma_f32_16x16x32_bf16(A[1][1], B1, acc1, 0,0,0);
      if(p < 324){
        #pragma unroll
        for(int r=0;r<4;r++){
          pre[(quad*4+r)*R1L + p]      = f2bf(acc0[r]);
          pre[(16+quad*4+r)*R1L + p]   = f2bf(acc1[r]);
        }
      }
    }
  }
  __syncthreads();

  // ---- phase 3: depthwise 3x3 (4 groups of 8ch), VALU ----
  int y = tid>>4, xx = tid&15;
  float acc[32];
  #pragma unroll
  for(int i=0;i<32;i++) acc[i]=0.f;
  #pragma unroll
  for(int g=0;g<4;g++){
    #pragma unroll
    for(int dy=0;dy<3;dy++){
      #pragma unroll
      for(int dx=0;dx<3;dx++){
        float iv[8];
        #pragma unroll
        for(int i=0;i<8;i++) iv[i] = bf2f(pre[(g*8+i)*R1L + (y+dy)*18 + xx+dx]);
        #pragma unroll
        for(int oc=0;oc<8;oc++){
          const float* wp = dw + (size_t)(cb+g*8+oc)*72 + dy*3 + dx;  // uniform -> s_load
          float s = acc[g*8+oc];
          #pragma unroll
          for(int i=0;i<8;i++) s += wp[i*9]*iv[i];
          acc[g*8+oc] = s;
        }
      }
    }
  }
  int pos = (ty0+y)*128 + tx0+xx;
  ushort_t* dst = qkvd + ((size_t)b*1152 + cb)*HW + pos;
  #pragma unroll
  for(int o=0;o<32;o++) dst[(size_t)o*HW] = f2bf(acc[o]);
}

// partial S per block + q/k norm^2: Spart[b][h][blk][c*48+d] over 512 positions
__global__ __launch_bounds__(256) void k_S(const ushort_t* __restrict__ qkvd,
                                           float* __restrict__ Spart,
                                           float* __restrict__ qn2){
  __shared__ float qk[96][132];   // 50688 B
  int tid = threadIdx.x;
  int blk = blockIdx.x;           // 32 per (b,h), each 4 chunks of 128 pos
  int h = blockIdx.y, b = blockIdx.z;
  int wave = tid>>6, lane = tid&63;
  int ci0 = (lane>>3)*6, di0 = (lane&7)*6;
  float sacc[6][6];
  #pragma unroll
  for(int i=0;i<6;i++)
    #pragma unroll
    for(int j=0;j<6;j++) sacc[i][j]=0.f;
  float nacc = 0.f;
  const ushort_t* qb = qkvd + ((size_t)b*1152 + h*48)*HW;
  const ushort_t* kb = qb + (size_t)384*HW;
  for(int chunk=0;chunk<4;chunk++){
    int p0 = (blk*4+chunk)*128;
    __syncthreads();
    #pragma unroll 4
    for(int it=0; it<24; it++){
      int e = tid + it*256;            // 96 rows x 64 ushort2
      int ch = e>>6, cc = (e&63)*2;
      const ushort_t* src = (ch<48) ? (qb + (size_t)ch*HW) : (kb + (size_t)(ch-48)*HW);
      uint32_t u = *(const uint32_t*)(src + p0 + cc);
      qk[ch][cc]   = bf2f((ushort_t)(u & 0xffff));
      qk[ch][cc+1] = bf2f((ushort_t)(u >> 16));
    }
    __syncthreads();
    if(tid < 96){
      const float* row = &qk[tid][0];
      float n0=0.f, n1=0.f;
      #pragma unroll 8
      for(int p=0;p<128;p+=2){ n0 += row[p]*row[p]; n1 += row[p+1]*row[p+1]; }
      nacc += n0 + n1;
    }
    int pb = wave*32;
    #pragma unroll 2
    for(int pp=0; pp<32; pp+=2){
      int p = pb+pp;
      float2 qv[6], kv[6];
      #pragma unroll
      for(int i=0;i<6;i++) qv[i] = *(const float2*)&qk[ci0+i][p];
      #pragma unroll
      for(int j=0;j<6;j++) kv[j] = *(const float2*)&qk[48+di0+j][p];
      #pragma unroll
      for(int i=0;i<6;i++)
        #pragma unroll
        for(int j=0;j<6;j++){
          sacc[i][j] += qv[i].x*kv[j].x;
          sacc[i][j] += qv[i].y*kv[j].y;
        }
    }
  }
  __syncthreads();
  float* scr = &qk[0][0];   // reuse LDS: 4*2304 = 9216 floats <= 12672
  #pragma unroll
  for(int i=0;i<6;i++)
    #pragma unroll
    for(int j=0;j<6;j++)
      scr[wave*2304 + (ci0+i)*48 + di0+j] = sacc[i][j];
  __syncthreads();
  float* outp = Spart + ((size_t)((b*HEADS+h)*32 + blk))*2304;
  for(int idx=tid; idx<2304; idx+=256){
    outp[idx] = scr[idx] + scr[2304+idx] + scr[4608+idx] + scr[6912+idx];
  }
  if(tid < 48)       atomicAdd(qn2 + (size_t)b*D1 + h*48 + tid, nacc);
  else if(tid < 96)  atomicAdd(qn2 + 1536 + (size_t)b*D1 + h*48 + (tid-48), nacc);
}

// per b: l-stats from x-stats -> dwconv-mean -> fc1 -> relu -> fc2 -> swish -> constv = po1@L
__global__ __launch_bounds__(384) void k_mlp(const float* __restrict__ xst,
                                             const float* __restrict__ qw,
                                             const float* __restrict__ dw,
                                             const float* __restrict__ fc1w,
                                             const float* __restrict__ fc1b,
                                             const float* __restrict__ fc2w,
                                             const float* __restrict__ fc2b,
                                             const float* __restrict__ po1,
                                             float* __restrict__ constv){
  int b = blockIdx.x, tid = threadIdx.x;
  __shared__ float xsl[432];
  __shared__ float lst[3456];
  __shared__ float avg[384];
  __shared__ float y1[24];
  __shared__ float Lb[384];
  for(int i=tid;i<432;i+=384) xsl[i] = xst[(size_t)b*432 + i];
  __syncthreads();
  {
    float st[9];
    #pragma unroll
    for(int s=0;s<9;s++) st[s]=0.f;
    const float* w = qw + (size_t)(1152+tid)*48;
    for(int c=0;c<48;c++){
      float wv = w[c];
      #pragma unroll
      for(int s=0;s<9;s++) st[s] += wv*xsl[c*9+s];
    }
    #pragma unroll
    for(int s=0;s<9;s++) lst[tid*9+s] = st[s];
  }
  __syncthreads();
  {
    int base = tid & ~7;
    const float* ls = &lst[base*9];
    float s = 0.f;
    #pragma unroll
    for(int i=0;i<8;i++){
      float T=ls[i*9+0],R0=ls[i*9+1],R1=ls[i*9+2],C0=ls[i*9+3],C1=ls[i*9+4];
      float c00=ls[i*9+5],c0W=ls[i*9+6],cH0=ls[i*9+7],cHW=ls[i*9+8];
      const float* wp = dw + (size_t)(1152+tid)*72 + i*9;
      #pragma unroll
      for(int dy=0;dy<3;dy++){
        float rm = (dy==0)?R1:((dy==2)?R0:0.f);
        #pragma unroll
        for(int dx=0;dx<3;dx++){
          float cm = (dx==0)?C1:((dx==2)?C0:0.f);
          float corner = 0.f;
          if(dy==0&&dx==0)corner=cHW;
          if(dy==0&&dx==2)corner=cH0;
          if(dy==2&&dx==0)corner=c0W;
          if(dy==2&&dx==2)corner=c00;
          s += wp[dy*3+dx]*(T-rm-cm+corner);
        }
      }
    }
    avg[tid] = s*(1.f/16384.f);
  }
  __syncthreads();
  if(tid<24){
    float s = fc1b[tid];
    const float* w = fc1w + (size_t)tid*384;
    for(int c=0;c<384;c++) s += w[c]*avg[c];
    y1[tid] = fmaxf(s,0.f);
  }
  __syncthreads();
  {
    float s = fc2b[tid];
    const float* w = fc2w + (size_t)tid*24;
    #pragma unroll
    for(int j=0;j<24;j++) s += w[j]*y1[j];
    Lb[tid] = s/(1.f+__expf(-s));
  }
  __syncthreads();
  if(tid<48){
    const float* w = po1 + (size_t)tid*384;
    float s = 0.f;
    for(int c=0;c<384;c++) s += w[c]*Lb[c];
    constv[b*48+tid] = s;
  }
}

// per (b,h): sum Spart, normalize, softmax, m2t[b][h*48+d][o] = sum_c po1[o][h*48+c]*attn[c][d]
__global__ __launch_bounds__(256) void k_attn(const float* __restrict__ Spart,
                                              const float* __restrict__ qn2,
                                              const float* __restrict__ temp,
                                              const float* __restrict__ po1,
                                              float* __restrict__ m2t){
  int h = blockIdx.x, b = blockIdx.y, tid = threadIdx.x;
  __shared__ float att[2304];
  __shared__ float nq[48], nk[48];
  const float* kn2 = qn2 + 1536;
  if(tid<48)      nq[tid]    = fmaxf(sqrtf(qn2[(size_t)b*D1 + h*48 + tid]),    1e-12f);
  else if(tid<96) nk[tid-48] = fmaxf(sqrtf(kn2[(size_t)b*D1 + h*48 + tid-48]), 1e-12f);
  __syncthreads();
  float tmp = temp[h];
  const float* Sp = Spart + ((size_t)(b*HEADS+h)*32)*2304;
  for(int idx=tid; idx<2304; idx+=256){
    float s = 0.f;
    for(int blk=0;blk<32;blk++) s += Sp[(size_t)blk*2304 + idx];
    int c = idx/48, d = idx - c*48;
    att[idx] = s*tmp/(nq[c]*nk[d]);
  }
  __syncthreads();
  if(tid<48){
    float* row = &att[tid*48];
    float m = -1e30f;
    for(int d=0;d<48;d++) m = fmaxf(m,row[d]);
    float s = 0.f;
    for(int d=0;d<48;d++){ float e=__expf(row[d]-m); row[d]=e; s+=e; }
    float inv = 1.f/s;
    for(int d=0;d<48;d++) row[d]*=inv;
  }
  __syncthreads();
  for(int idx=tid; idx<2304; idx+=256){
    int d = idx/48, o = idx - d*48;
    float s = 0.f;
    for(int c=0;c<48;c++) s += po1[(size_t)o*D1 + h*48 + c]*att[c*48+d];
    m2t[((size_t)b*D1 + h*48 + d)*48 + o] = s;
  }
}

// out[b][o][pos] = x + constv[o] + sum_hd m2t[b][hd][o]*v[b][hd][pos]
__global__ __launch_bounds__(256) void k_final(const ushort_t* __restrict__ qkvd,
                                               const float* __restrict__ m2t,
                                               const float* __restrict__ constv,
                                               const float* __restrict__ x,
                                               float* __restrict__ out){
  int tid = threadIdx.x;
  int pos = blockIdx.x*256 + tid;
  int b   = blockIdx.y;
  const ushort_t* vbase = qkvd + ((size_t)b*1152 + 768)*HW + pos;
  const float* m2 = m2t + (size_t)b*D1*48;
  float acc[48];
  #pragma unroll
  for(int o=0;o<48;o++) acc[o]=0.f;
  for(int ch=0;ch<384;ch+=8){
    float vv[8];
    #pragma unroll
    for(int j=0;j<8;j++) vv[j] = bf2f(vbase[(size_t)(ch+j)*HW]);
    #pragma unroll
    for(int j=0;j<8;j++){
      const float* mrow = m2 + (size_t)(ch+j)*48;   // uniform -> scalar loads
      #pragma unroll
      for(int o=0;o<48;o++) acc[o] += mrow[o]*vv[j];
    }
  }
  const float* xb = x   + (size_t)b*CC*HW + pos;
  float*       ob = out + (size_t)b*CC*HW + pos;
  const float* cv = constv + b*48;
  #pragma unroll
  for(int o=0;o<48;o++) ob[(size_t)o*HW] = xb[(size_t)o*HW] + cv[o] + acc[o];
}

extern "C" void kernel_launch(void* const* d_in, const int* in_sizes, int n_in,
                              void* d_out, int out_size, void* d_ws, size_t ws_size,
                              hipStream_t stream){
  const float* x    = (const float*)d_in[0];
  const float* qw   = (const float*)d_in[1];
  const float* dw   = (const float*)d_in[2];
  const float* po1  = (const float*)d_in[3];
  const float* fc1w = (const float*)d_in[4];
  const float* fc1b = (const float*)d_in[5];
  const float* fc2w = (const float*)d_in[6];
  const float* fc2b = (const float*)d_in[7];
  const float* temp = (const float*)d_in[8];
  float* out = (float*)d_out;
  char* ws = (char*)d_ws;

  // workspace layout (total ~160.75 MB, known-good)
  ushort_t* qkvd   = (ushort_t*)(ws);                 // 4*1152*16384*2 = 150,994,944
  float*    Spart  = (float*)(ws + 150994944);        // 4*8*32*2304*4 = 9,437,184
  float*    qn2    = (float*)(ws + 160432128);        // 6144 B (kn2 = qn2+1536 floats)
  float*    xst    = (float*)(ws + 160444416);        // 6912
  float*    constv = (float*)(ws + 160451328);        // 768
  float*    m2t    = (float*)(ws + 160452096);        // 294912

  k_zero  <<<dim3(12),           256, 0, stream>>>(qn2, 3072);
  k_xstats<<<dim3(48,BB),        256, 0, stream>>>(x, xst);
  k_conv  <<<dim3(64,36,BB),     256, 0, stream>>>(x, qw, dw, qkvd);
  k_S     <<<dim3(32,HEADS,BB),  256, 0, stream>>>(qkvd, Spart, qn2);
  k_mlp   <<<dim3(BB),           384, 0, stream>>>(xst, qw, dw, fc1w, fc1b, fc2w, fc2b, po1, constv);
  k_attn  <<<dim3(HEADS,BB),     256, 0, stream>>>(Spart, qn2, temp, po1, m2t);
  k_final <<<dim3(64,BB),        256, 0, stream>>>(qkvd, m2t, constv, x, out);
}

// Round 4
// 487.418 us; speedup vs baseline: 3.7879x; 1.5116x over previous
//
#include <hip/hip_runtime.h>
#include <cstdint>

#define BB 4
#define CC 48
#define HW 16384
#define D1 384
#define HEADS 8

typedef unsigned short ushort_t;
typedef __attribute__((ext_vector_type(8))) short short8;
typedef __attribute__((ext_vector_type(4))) float f32x4;

__device__ __forceinline__ float bf2f(ushort_t u){
  union{uint32_t i; float f;} v; v.i = ((uint32_t)u)<<16; return v.f;
}
__device__ __forceinline__ ushort_t f2bf(float f){
  union{float f; uint32_t i;} v; v.f=f;
  uint32_t x = v.i;
  uint32_t r = (x + 0x7fff + ((x>>16)&1)) >> 16;
  return (ushort_t)r;
}

__global__ __launch_bounds__(256) void k_zero(float* p, int n){
  int i = blockIdx.x*256 + threadIdx.x;
  if(i<n) p[i]=0.f;
}

// fused-weight precompute: Wfp[oc][kk], kk = t*48+c (t<9), zero-padded to 448.
// Wf[oc][t*48+c] = sum_j dw[oc][j][t] * qw[8*(oc/8)+j][c]
__global__ __launch_bounds__(256) void k_wf(const float* __restrict__ dw,
                                            const float* __restrict__ qw,
                                            ushort_t* __restrict__ wfp){
  int oc = blockIdx.x, tid = threadIdx.x;
  for(int kk=tid; kk<448; kk+=256){
    int t = kk/48, c = kk - t*48;
    float s = 0.f;
    if(t < 9){
      #pragma unroll
      for(int j=0;j<8;j++)
        s += dw[(size_t)oc*72 + j*9 + t] * qw[(size_t)((oc>>3)*8 + j)*48 + c];
    }
    wfp[(size_t)oc*448 + kk] = f2bf(s);
  }
}

// 9 boundary stats per (b, x-channel): T, row0, row127, col0, col127, 4 corners
__global__ __launch_bounds__(256) void k_xstats(const float* __restrict__ x,
                                                float* __restrict__ xst){
  int ch = blockIdx.x, b = blockIdx.y;
  const float* p = x + ((size_t)b*CC + ch)*HW;
  int tid = threadIdx.x;
  float T=0,R0=0,R1=0,C0=0,C1=0;
  for(int i=tid;i<HW;i+=256){
    float v = p[i];
    T += v;
    if(i<128)      R0 += v;
    if(i>=16256)   R1 += v;
    int xc = i & 127;
    if(xc==0)      C0 += v;
    if(xc==127)    C1 += v;
  }
  __shared__ float red[20];
  for(int off=32;off;off>>=1){
    T  += __shfl_down(T,off);  R0 += __shfl_down(R0,off); R1 += __shfl_down(R1,off);
    C0 += __shfl_down(C0,off); C1 += __shfl_down(C1,off);
  }
  int wv = tid>>6, ln = tid&63;
  if(ln==0){ red[wv]=T; red[4+wv]=R0; red[8+wv]=R1; red[12+wv]=C0; red[16+wv]=C1; }
  __syncthreads();
  if(tid==0){
    float* o = xst + ((size_t)b*CC + ch)*9;
    o[0]=red[0]+red[1]+red[2]+red[3];
    o[1]=red[4]+red[5]+red[6]+red[7];
    o[2]=red[8]+red[9]+red[10]+red[11];
    o[3]=red[12]+red[13]+red[14]+red[15];
    o[4]=red[16]+red[17]+red[18]+red[19];
    o[5]=p[0]; o[6]=p[127]; o[7]=p[16256]; o[8]=p[16383];
  }
}

// dense 3x3 conv 48->1152 as MFMA GEMM: qkvd[oc][pos] = sum_kk Wfp[oc][kk]*B[kk][pos]
// B[kk=t*48+c][pos] = x[c][pos+off(t)]; halo position-major in LDS.
// Block: M=128 oc x N=128 pos (spatial 8 tall x 16 wide); 4 waves, each 64x64.
#define HROW 56   // padded row length (u16) => 112 B, stride 28 dwords: 2-way free
__global__ __launch_bounds__(256,3) void k_conv(const float* __restrict__ x,
                                                const ushort_t* __restrict__ wfp,
                                                ushort_t* __restrict__ qkvd){
  __shared__ ushort_t xs[180*HROW];   // 20160 B
  int tid  = threadIdx.x;
  int wave = tid>>6, lane = tid&63;
  int quad = lane>>4, mrow = lane&15;
  int mhalf = wave>>1, nhalf = wave&1;
  int tile = blockIdx.x;              // 128 tiles: 16 (y) x 8 (x)
  int ty0 = (tile>>3)*8, tx0 = (tile&7)*16;
  int ocb = blockIdx.y*128 + mhalf*64;
  int b   = blockIdx.z;

  // ---- stage halo: xs[r][c], r = hy*18+hx (10x18), bf16 ----
  const float* xb = x + (size_t)b*CC*HW;
  for(int idx=tid; idx<8640; idx+=256){
    int c = idx/180, r = idx - c*180;
    int hy = r/18, hx = r - hy*18;
    int gy = ty0 + hy - 1, gx = tx0 + hx - 1;
    float v = 0.f;
    if((unsigned)gy < 128u && (unsigned)gx < 128u)
      v = xb[(size_t)c*HW + gy*128 + gx];
    xs[r*HROW + c] = f2bf(v);
  }
  __syncthreads();

  // ---- K-loop: 14 chunks of 32 ----
  f32x4 Cacc[4][4];
  #pragma unroll
  for(int mt=0;mt<4;mt++)
    #pragma unroll
    for(int nt=0;nt<4;nt++) Cacc[mt][nt] = (f32x4){0.f,0.f,0.f,0.f};

  // per-lane B base byte addr per nt: row = (py+1)*18 + (px+1)
  int baseByte[4];
  #pragma unroll
  for(int nt=0;nt<4;nt++){
    int py = nhalf*4 + nt;
    baseByte[nt] = ((py+1)*18 + mrow + 1) * (HROW*2);
  }
  const ushort_t* Abase = wfp + (size_t)(ocb + mrow)*448;

  #pragma unroll
  for(int chunk=0; chunk<14; chunk++){
    int kq = chunk*32 + quad*8;
    int t  = kq/48;               // 0..9 (9 only chunk 13, quads 2,3)
    int c  = kq - t*48;           // 0..47 (for t=9: 0..15)
    int tc = (t<9) ? t : 8;       // clamp row (A is zero there, B junk is fine)
    int dy = tc/3, dx = tc - dy*3;
    int rel = ((dy-1)*18 + (dx-1))*(HROW*2) + c*2;

    short8 Af[4];
    #pragma unroll
    for(int mt=0;mt<4;mt++)
      Af[mt] = *(const short8*)(Abase + (size_t)mt*16*448 + chunk*32 + quad*8);
    short8 Bf[4];
    #pragma unroll
    for(int nt=0;nt<4;nt++)
      Bf[nt] = *(const short8*)((const char*)xs + baseByte[nt] + rel);
    #pragma unroll
    for(int mt=0;mt<4;mt++)
      #pragma unroll
      for(int nt=0;nt<4;nt++)
        Cacc[mt][nt] = __builtin_amdgcn_mfma_f32_16x16x32_bf16(Af[mt], Bf[nt], Cacc[mt][nt], 0,0,0);
  }

  // ---- epilogue: C layout col=lane&15, row=quad*4+reg ----
  #pragma unroll
  for(int mt=0;mt<4;mt++){
    #pragma unroll
    for(int nt=0;nt<4;nt++){
      int py = nhalf*4 + nt;
      int gpos = (ty0+py)*128 + tx0 + mrow;
      #pragma unroll
      for(int r=0;r<4;r++){
        int oc = ocb + mt*16 + quad*4 + r;
        qkvd[((size_t)b*1152 + oc)*HW + gpos] = f2bf(Cacc[mt][nt][r]);
      }
    }
  }
}

// partial S per block + q/k norm^2: Spart[b][h][blk][c*48+d] over 512 positions
__global__ __launch_bounds__(256) void k_S(const ushort_t* __restrict__ qkvd,
                                           float* __restrict__ Spart,
                                           float* __restrict__ qn2){
  __shared__ float qk[96][132];   // 50688 B
  int tid = threadIdx.x;
  int blk = blockIdx.x;           // 32 per (b,h), each 4 chunks of 128 pos
  int h = blockIdx.y, b = blockIdx.z;
  int wave = tid>>6, lane = tid&63;
  int ci0 = (lane>>3)*6, di0 = (lane&7)*6;
  float sacc[6][6];
  #pragma unroll
  for(int i=0;i<6;i++)
    #pragma unroll
    for(int j=0;j<6;j++) sacc[i][j]=0.f;
  float nacc = 0.f;
  const ushort_t* qb = qkvd + ((size_t)b*1152 + h*48)*HW;
  const ushort_t* kb = qb + (size_t)384*HW;
  for(int chunk=0;chunk<4;chunk++){
    int p0 = (blk*4+chunk)*128;
    __syncthreads();
    #pragma unroll 4
    for(int it=0; it<24; it++){
      int e = tid + it*256;            // 96 rows x 64 ushort2
      int ch = e>>6, cc = (e&63)*2;
      const ushort_t* src = (ch<48) ? (qb + (size_t)ch*HW) : (kb + (size_t)(ch-48)*HW);
      uint32_t u = *(const uint32_t*)(src + p0 + cc);
      qk[ch][cc]   = bf2f((ushort_t)(u & 0xffff));
      qk[ch][cc+1] = bf2f((ushort_t)(u >> 16));
    }
    __syncthreads();
    if(tid < 96){
      const float* row = &qk[tid][0];
      float n0=0.f, n1=0.f;
      #pragma unroll 8
      for(int p=0;p<128;p+=2){ n0 += row[p]*row[p]; n1 += row[p+1]*row[p+1]; }
      nacc += n0 + n1;
    }
    int pb = wave*32;
    #pragma unroll 2
    for(int pp=0; pp<32; pp+=2){
      int p = pb+pp;
      float2 qv[6], kv[6];
      #pragma unroll
      for(int i=0;i<6;i++) qv[i] = *(const float2*)&qk[ci0+i][p];
      #pragma unroll
      for(int j=0;j<6;j++) kv[j] = *(const float2*)&qk[48+di0+j][p];
      #pragma unroll
      for(int i=0;i<6;i++)
        #pragma unroll
        for(int j=0;j<6;j++){
          sacc[i][j] += qv[i].x*kv[j].x;
          sacc[i][j] += qv[i].y*kv[j].y;
        }
    }
  }
  __syncthreads();
  float* scr = &qk[0][0];
  #pragma unroll
  for(int i=0;i<6;i++)
    #pragma unroll
    for(int j=0;j<6;j++)
      scr[wave*2304 + (ci0+i)*48 + di0+j] = sacc[i][j];
  __syncthreads();
  float* outp = Spart + ((size_t)((b*HEADS+h)*32 + blk))*2304;
  for(int idx=tid; idx<2304; idx+=256){
    outp[idx] = scr[idx] + scr[2304+idx] + scr[4608+idx] + scr[6912+idx];
  }
  if(tid < 48)       atomicAdd(qn2 + (size_t)b*D1 + h*48 + tid, nacc);
  else if(tid < 96)  atomicAdd(qn2 + 1536 + (size_t)b*D1 + h*48 + (tid-48), nacc);
}

// per b: l-stats from x-stats -> dwconv-mean -> fc1 -> relu -> fc2 -> swish -> constv = po1@L
__global__ __launch_bounds__(384) void k_mlp(const float* __restrict__ xst,
                                             const float* __restrict__ qw,
                                             const float* __restrict__ dw,
                                             const float* __restrict__ fc1w,
                                             const float* __restrict__ fc1b,
                                             const float* __restrict__ fc2w,
                                             const float* __restrict__ fc2b,
                                             const float* __restrict__ po1,
                                             float* __restrict__ constv){
  int b = blockIdx.x, tid = threadIdx.x;
  __shared__ float xsl[432];
  __shared__ float lst[3456];
  __shared__ float avg[384];
  __shared__ float y1[24];
  __shared__ float Lb[384];
  for(int i=tid;i<432;i+=384) xsl[i] = xst[(size_t)b*432 + i];
  __syncthreads();
  {
    float st[9];
    #pragma unroll
    for(int s=0;s<9;s++) st[s]=0.f;
    const float* w = qw + (size_t)(1152+tid)*48;
    for(int c=0;c<48;c++){
      float wv = w[c];
      #pragma unroll
      for(int s=0;s<9;s++) st[s] += wv*xsl[c*9+s];
    }
    #pragma unroll
    for(int s=0;s<9;s++) lst[tid*9+s] = st[s];
  }
  __syncthreads();
  {
    int base = tid & ~7;
    const float* ls = &lst[base*9];
    float s = 0.f;
    #pragma unroll
    for(int i=0;i<8;i++){
      float T=ls[i*9+0],R0=ls[i*9+1],R1=ls[i*9+2],C0=ls[i*9+3],C1=ls[i*9+4];
      float c00=ls[i*9+5],c0W=ls[i*9+6],cH0=ls[i*9+7],cHW=ls[i*9+8];
      const float* wp = dw + (size_t)(1152+tid)*72 + i*9;
      #pragma unroll
      for(int dy=0;dy<3;dy++){
        float rm = (dy==0)?R1:((dy==2)?R0:0.f);
        #pragma unroll
        for(int dx=0;dx<3;dx++){
          float cm = (dx==0)?C1:((dx==2)?C0:0.f);
          float corner = 0.f;
          if(dy==0&&dx==0)corner=cHW;
          if(dy==0&&dx==2)corner=cH0;
          if(dy==2&&dx==0)corner=c0W;
          if(dy==2&&dx==2)corner=c00;
          s += wp[dy*3+dx]*(T-rm-cm+corner);
        }
      }
    }
    avg[tid] = s*(1.f/16384.f);
  }
  __syncthreads();
  if(tid<24){
    float s = fc1b[tid];
    const float* w = fc1w + (size_t)tid*384;
    for(int c=0;c<384;c++) s += w[c]*avg[c];
    y1[tid] = fmaxf(s,0.f);
  }
  __syncthreads();
  {
    float s = fc2b[tid];
    const float* w = fc2w + (size_t)tid*24;
    #pragma unroll
    for(int j=0;j<24;j++) s += w[j]*y1[j];
    Lb[tid] = s/(1.f+__expf(-s));
  }
  __syncthreads();
  if(tid<48){
    const float* w = po1 + (size_t)tid*384;
    float s = 0.f;
    for(int c=0;c<384;c++) s += w[c]*Lb[c];
    constv[b*48+tid] = s;
  }
}

// per (b,h): sum Spart, normalize, softmax, m2t[b][h*48+d][o] = sum_c po1[o][h*48+c]*attn[c][d]
__global__ __launch_bounds__(256) void k_attn(const float* __restrict__ Spart,
                                              const float* __restrict__ qn2,
                                              const float* __restrict__ temp,
                                              const float* __restrict__ po1,
                                              float* __restrict__ m2t){
  int h = blockIdx.x, b = blockIdx.y, tid = threadIdx.x;
  __shared__ float att[2304];
  __shared__ float nq[48], nk[48];
  const float* kn2 = qn2 + 1536;
  if(tid<48)      nq[tid]    = fmaxf(sqrtf(qn2[(size_t)b*D1 + h*48 + tid]),    1e-12f);
  else if(tid<96) nk[tid-48] = fmaxf(sqrtf(kn2[(size_t)b*D1 + h*48 + tid-48]), 1e-12f);
  __syncthreads();
  float tmp = temp[h];
  const float* Sp = Spart + ((size_t)(b*HEADS+h)*32)*2304;
  for(int idx=tid; idx<2304; idx+=256){
    float s = 0.f;
    for(int blk=0;blk<32;blk++) s += Sp[(size_t)blk*2304 + idx];
    int c = idx/48, d = idx - c*48;
    att[idx] = s*tmp/(nq[c]*nk[d]);
  }
  __syncthreads();
  if(tid<48){
    float* row = &att[tid*48];
    float m = -1e30f;
    for(int d=0;d<48;d++) m = fmaxf(m,row[d]);
    float s = 0.f;
    for(int d=0;d<48;d++){ float e=__expf(row[d]-m); row[d]=e; s+=e; }
    float inv = 1.f/s;
    for(int d=0;d<48;d++) row[d]*=inv;
  }
  __syncthreads();
  for(int idx=tid; idx<2304; idx+=256){
    int d = idx/48, o = idx - d*48;
    float s = 0.f;
    for(int c=0;c<48;c++) s += po1[(size_t)o*D1 + h*48 + c]*att[c*48+d];
    m2t[((size_t)b*D1 + h*48 + d)*48 + o] = s;
  }
}

// out[b][o][pos] = x + constv[o] + sum_hd m2t[b][hd][o]*v[b][hd][pos]
__global__ __launch_bounds__(256) void k_final(const ushort_t* __restrict__ qkvd,
                                               const float* __restrict__ m2t,
                                               const float* __restrict__ constv,
                                               const float* __restrict__ x,
                                               float* __restrict__ out){
  int tid = threadIdx.x;
  int pos = blockIdx.x*256 + tid;
  int b   = blockIdx.y;
  const ushort_t* vbase = qkvd + ((size_t)b*1152 + 768)*HW + pos;
  const float* m2 = m2t + (size_t)b*D1*48;
  float acc[48];
  #pragma unroll
  for(int o=0;o<48;o++) acc[o]=0.f;
  for(int ch=0;ch<384;ch+=8){
    float vv[8];
    #pragma unroll
    for(int j=0;j<8;j++) vv[j] = bf2f(vbase[(size_t)(ch+j)*HW]);
    #pragma unroll
    for(int j=0;j<8;j++){
      const float* mrow = m2 + (size_t)(ch+j)*48;   // uniform -> scalar loads
      #pragma unroll
      for(int o=0;o<48;o++) acc[o] += mrow[o]*vv[j];
    }
  }
  const float* xb = x   + (size_t)b*CC*HW + pos;
  float*       ob = out + (size_t)b*CC*HW + pos;
  const float* cv = constv + b*48;
  #pragma unroll
  for(int o=0;o<48;o++) ob[(size_t)o*HW] = xb[(size_t)o*HW] + cv[o] + acc[o];
}

extern "C" void kernel_launch(void* const* d_in, const int* in_sizes, int n_in,
                              void* d_out, int out_size, void* d_ws, size_t ws_size,
                              hipStream_t stream){
  const float* x    = (const float*)d_in[0];
  const float* qw   = (const float*)d_in[1];
  const float* dw   = (const float*)d_in[2];
  const float* po1  = (const float*)d_in[3];
  const float* fc1w = (const float*)d_in[4];
  const float* fc1b = (const float*)d_in[5];
  const float* fc2w = (const float*)d_in[6];
  const float* fc2b = (const float*)d_in[7];
  const float* temp = (const float*)d_in[8];
  float* out = (float*)d_out;
  char* ws = (char*)d_ws;

  // workspace layout (~161.8 MB)
  ushort_t* qkvd   = (ushort_t*)(ws);                 // 150,994,944
  float*    Spart  = (float*)(ws + 150994944);        // 9,437,184
  float*    qn2    = (float*)(ws + 160432128);        // 12,288 (qn2 + kn2)
  float*    xst    = (float*)(ws + 160444416);        // 6,912
  float*    constv = (float*)(ws + 160451328);        // 768
  float*    m2t    = (float*)(ws + 160452096);        // 294,912
  ushort_t* wfp    = (ushort_t*)(ws + 160747008);     // 1,032,192

  k_zero  <<<dim3(12),           256, 0, stream>>>(qn2, 3072);
  k_wf    <<<dim3(1152),         256, 0, stream>>>(dw, qw, wfp);
  k_xstats<<<dim3(48,BB),        256, 0, stream>>>(x, xst);
  k_conv  <<<dim3(128,9,BB),     256, 0, stream>>>(x, wfp, qkvd);
  k_S     <<<dim3(32,HEADS,BB),  256, 0, stream>>>(qkvd, Spart, qn2);
  k_mlp   <<<dim3(BB),           384, 0, stream>>>(xst, qw, dw, fc1w, fc1b, fc2w, fc2b, po1, constv);
  k_attn  <<<dim3(HEADS,BB),     256, 0, stream>>>(Spart, qn2, temp, po1, m2t);
  k_final <<<dim3(64,BB),        256, 0, stream>>>(qkvd, m2t, constv, x, out);
}

// Round 5
// 448.449 us; speedup vs baseline: 4.1170x; 1.0869x over previous
//
#include <hip/hip_runtime.h>
#include <cstdint>

#define BB 4
#define CC 48
#define HW 16384
#define D1 384
#define HEADS 8

typedef unsigned short ushort_t;
typedef __attribute__((ext_vector_type(8))) short short8;
typedef __attribute__((ext_vector_type(4))) float f32x4;

__device__ __forceinline__ float bf2f(ushort_t u){
  union{uint32_t i; float f;} v; v.i = ((uint32_t)u)<<16; return v.f;
}
__device__ __forceinline__ ushort_t f2bf(float f){
  union{float f; uint32_t i;} v; v.f=f;
  uint32_t x = v.i;
  uint32_t r = (x + 0x7fff + ((x>>16)&1)) >> 16;
  return (ushort_t)r;
}

__global__ __launch_bounds__(256) void k_zero(float* p, int n){
  int i = blockIdx.x*256 + threadIdx.x;
  if(i<n) p[i]=0.f;
}

// fused-weight precompute: Wfp[oc][kk], kk = t*48+c (t<9), zero-padded to 448.
__global__ __launch_bounds__(256) void k_wf(const float* __restrict__ dw,
                                            const float* __restrict__ qw,
                                            ushort_t* __restrict__ wfp){
  int oc = blockIdx.x, tid = threadIdx.x;
  for(int kk=tid; kk<448; kk+=256){
    int t = kk/48, c = kk - t*48;
    float s = 0.f;
    if(t < 9){
      #pragma unroll
      for(int j=0;j<8;j++)
        s += dw[(size_t)oc*72 + j*9 + t] * qw[(size_t)((oc>>3)*8 + j)*48 + c];
    }
    wfp[(size_t)oc*448 + kk] = f2bf(s);
  }
}

// 9 boundary stats per (b, x-channel)
__global__ __launch_bounds__(256) void k_xstats(const float* __restrict__ x,
                                                float* __restrict__ xst){
  int ch = blockIdx.x, b = blockIdx.y;
  const float* p = x + ((size_t)b*CC + ch)*HW;
  int tid = threadIdx.x;
  float T=0,R0=0,R1=0,C0=0,C1=0;
  for(int i=tid;i<HW;i+=256){
    float v = p[i];
    T += v;
    if(i<128)      R0 += v;
    if(i>=16256)   R1 += v;
    int xc = i & 127;
    if(xc==0)      C0 += v;
    if(xc==127)    C1 += v;
  }
  __shared__ float red[20];
  for(int off=32;off;off>>=1){
    T  += __shfl_down(T,off);  R0 += __shfl_down(R0,off); R1 += __shfl_down(R1,off);
    C0 += __shfl_down(C0,off); C1 += __shfl_down(C1,off);
  }
  int wv = tid>>6, ln = tid&63;
  if(ln==0){ red[wv]=T; red[4+wv]=R0; red[8+wv]=R1; red[12+wv]=C0; red[16+wv]=C1; }
  __syncthreads();
  if(tid==0){
    float* o = xst + ((size_t)b*CC + ch)*9;
    o[0]=red[0]+red[1]+red[2]+red[3];
    o[1]=red[4]+red[5]+red[6]+red[7];
    o[2]=red[8]+red[9]+red[10]+red[11];
    o[3]=red[12]+red[13]+red[14]+red[15];
    o[4]=red[16]+red[17]+red[18]+red[19];
    o[5]=p[0]; o[6]=p[127]; o[7]=p[16256]; o[8]=p[16383];
  }
}

// dense 3x3 conv 48->1152 as MFMA GEMM.
// Halo: xs[r][64] u16, r = hy*18+hx (10x18); group g (8ch) stored at slot (g ^ (r&7)).
#define HROWC 64
__global__ __launch_bounds__(256,3) void k_conv(const float* __restrict__ x,
                                                const ushort_t* __restrict__ wfp,
                                                ushort_t* __restrict__ qkvd){
  __shared__ __align__(16) ushort_t xs[180*HROWC];   // 23040 B
  int tid  = threadIdx.x;
  int wave = tid>>6, lane = tid&63;
  int quad = lane>>4, mrow = lane&15;
  int mhalf = wave>>1, nhalf = wave&1;
  int tile = blockIdx.x;              // 128 tiles: 16 (y) x 8 (x)
  int ty0 = (tile>>3)*8, tx0 = (tile&7)*16;
  int ocb = blockIdx.y*128 + mhalf*64;
  int b   = blockIdx.z;

  // ---- stage halo: per unit (g,r): 8 coalesced dword loads -> one b128 LDS write ----
  const float* xb = x + (size_t)b*CC*HW;
  for(int u=tid; u<1080; u+=256){      // 6 groups * 180 rows
    int g = u/180, r = u - g*180;
    int hy = r/18, hx = r - hy*18;
    int gy = ty0+hy-1, gx = tx0+hx-1;
    bool in = ((unsigned)gy<128u) && ((unsigned)gx<128u);
    const float* bp = xb + (size_t)(g<<3)*HW + (gy*128+gx);
    ushort_t tmp[8];
    #pragma unroll
    for(int j=0;j<8;j++){
      float v = in ? bp[(size_t)j*HW] : 0.f;
      tmp[j] = f2bf(v);
    }
    *(short8*)(xs + r*HROWC + ((g ^ (r&7))<<3)) = *(short8*)tmp;
  }
  __syncthreads();

  // ---- K-loop: 14 chunks of 32, A double-buffered in regs ----
  f32x4 Cacc[4][4];
  #pragma unroll
  for(int mt=0;mt<4;mt++)
    #pragma unroll
    for(int nt=0;nt<4;nt++) Cacc[mt][nt] = (f32x4){0.f,0.f,0.f,0.f};

  int rb[4];
  #pragma unroll
  for(int nt=0;nt<4;nt++) rb[nt] = (nhalf*4+nt+1)*18 + mrow + 1;
  const ushort_t* Abase = wfp + (size_t)(ocb + mrow)*448 + quad*8;

  short8 Ac[4], An[4];
  #pragma unroll
  for(int mt=0;mt<4;mt++) Ac[mt] = *(const short8*)(Abase + (size_t)mt*16*448);

  #pragma unroll
  for(int chunk=0; chunk<14; chunk++){
    if(chunk < 13){
      #pragma unroll
      for(int mt=0;mt<4;mt++)
        An[mt] = *(const short8*)(Abase + (size_t)mt*16*448 + (chunk+1)*32);
    }
    int kq = chunk*32 + quad*8;
    int t  = kq/48;
    int c  = kq - t*48;
    int tc = (t<9) ? t : 8;            // A is zero for t=9; B junk is harmless
    int dyq = tc/3;
    int drow = dyq*18 + (tc - dyq*3) - 19;
    int g = c>>3;
    short8 Bf[4];
    #pragma unroll
    for(int nt=0;nt<4;nt++){
      int r = rb[nt] + drow;
      Bf[nt] = *(const short8*)(xs + r*HROWC + ((g ^ (r&7))<<3));
    }
    #pragma unroll
    for(int mt=0;mt<4;mt++)
      #pragma unroll
      for(int nt=0;nt<4;nt++)
        Cacc[mt][nt] = __builtin_amdgcn_mfma_f32_16x16x32_bf16(Ac[mt], Bf[nt], Cacc[mt][nt], 0,0,0);
    #pragma unroll
    for(int mt=0;mt<4;mt++) Ac[mt] = An[mt];
  }

  // ---- epilogue: C layout col=lane&15 (pos), row=quad*4+reg (oc) ----
  #pragma unroll
  for(int mt=0;mt<4;mt++){
    #pragma unroll
    for(int nt=0;nt<4;nt++){
      int py = nhalf*4 + nt;
      int gpos = (ty0+py)*128 + tx0 + mrow;
      #pragma unroll
      for(int r=0;r<4;r++){
        int oc = ocb + mt*16 + quad*4 + r;
        qkvd[((size_t)b*1152 + oc)*HW + gpos] = f2bf(Cacc[mt][nt][r]);
      }
    }
  }
}

// S = Q K^T per (b,h) via MFMA; norms free as diag(Q Q^T), diag(K K^T).
// Block: 512 positions (2 tiles of 256); wave w covers K-slice w*64..+64.
__global__ __launch_bounds__(256,3) void k_S(const ushort_t* __restrict__ qkvd,
                                             float* __restrict__ Spart,
                                             float* __restrict__ qn2){
  __shared__ __align__(16) ushort_t qk[96*264];   // 50688 B; rows 0..47 q, 48..95 k
  int tid = threadIdx.x;
  int blk = blockIdx.x, h = blockIdx.y, b = blockIdx.z;
  int wave = tid>>6, lane = tid&63;
  int quad = lane>>4, mrow = lane&15;
  const ushort_t* qb = qkvd + ((size_t)b*1152 + h*48)*HW;
  const ushort_t* kb = qb + (size_t)384*HW;

  f32x4 accS[3][3], accq[3], acck[3];
  #pragma unroll
  for(int mt=0;mt<3;mt++){
    accq[mt] = (f32x4){0.f,0.f,0.f,0.f};
    acck[mt] = (f32x4){0.f,0.f,0.f,0.f};
    #pragma unroll
    for(int nt=0;nt<3;nt++) accS[mt][nt] = (f32x4){0.f,0.f,0.f,0.f};
  }

  for(int half=0; half<2; half++){
    int p0 = blk*512 + half*256;
    __syncthreads();
    for(int u=tid; u<3072; u+=256){            // 96 ch x 32 b128-units
      int ch = u>>5, px = u&31;
      const ushort_t* src = ((ch<48) ? qb + (size_t)ch*HW
                                     : kb + (size_t)(ch-48)*HW) + p0 + px*8;
      *(short8*)(qk + ch*264 + px*8) = *(const short8*)src;
    }
    __syncthreads();
    #pragma unroll
    for(int ks=0; ks<2; ks++){
      int koff = wave*64 + ks*32 + quad*8;
      short8 Aq[3], Bk[3];
      #pragma unroll
      for(int mt=0;mt<3;mt++) Aq[mt] = *(const short8*)(qk + (mt*16+mrow)*264 + koff);
      #pragma unroll
      for(int nt=0;nt<3;nt++) Bk[nt] = *(const short8*)(qk + (48+nt*16+mrow)*264 + koff);
      #pragma unroll
      for(int mt=0;mt<3;mt++){
        accq[mt] = __builtin_amdgcn_mfma_f32_16x16x32_bf16(Aq[mt], Aq[mt], accq[mt], 0,0,0);
        acck[mt] = __builtin_amdgcn_mfma_f32_16x16x32_bf16(Bk[mt], Bk[mt], acck[mt], 0,0,0);
        #pragma unroll
        for(int nt=0;nt<3;nt++)
          accS[mt][nt] = __builtin_amdgcn_mfma_f32_16x16x32_bf16(Aq[mt], Bk[nt], accS[mt][nt], 0,0,0);
      }
    }
  }
  __syncthreads();
  float* scr = (float*)qk;     // 4 waves x 2304 f32 = 36864 B
  #pragma unroll
  for(int mt=0;mt<3;mt++)
    #pragma unroll
    for(int nt=0;nt<3;nt++)
      #pragma unroll
      for(int r=0;r<4;r++)
        scr[wave*2304 + (mt*16+quad*4+r)*48 + nt*16 + mrow] = accS[mt][nt][r];
  __syncthreads();
  float* outp = Spart + ((size_t)((b*HEADS+h)*32 + blk))*2304;
  for(int idx=tid; idx<2304; idx+=256)
    outp[idx] = scr[idx] + scr[2304+idx] + scr[4608+idx] + scr[6912+idx];
  // norms: diag lanes satisfy col(=mrow) == row(=quad*4+r)
  int rr = mrow - (quad<<2);
  #pragma unroll
  for(int r=0;r<4;r++){
    if(rr == r){
      #pragma unroll
      for(int mt=0;mt<3;mt++){
        atomicAdd(qn2 + (size_t)b*D1 + h*48 + mt*16 + mrow, accq[mt][r]);
        atomicAdd(qn2 + 1536 + (size_t)b*D1 + h*48 + mt*16 + mrow, acck[mt][r]);
      }
    }
  }
}

// reduce Spart over 32 blocks -> Sred[bh][2304]
__global__ __launch_bounds__(256) void k_sred(const float* __restrict__ Spart,
                                              float* __restrict__ Sred){
  int idx = blockIdx.x*256 + threadIdx.x;   // 73728 total
  int bh = idx/2304, e = idx - bh*2304;
  const float* p = Spart + (size_t)bh*32*2304 + e;
  float s = 0.f;
  #pragma unroll
  for(int blk=0; blk<32; blk++) s += p[(size_t)blk*2304];
  Sred[idx] = s;
}

// per b: l-stats from x-stats -> mean -> fc1 -> relu -> fc2 -> swish -> constv = po1@L
__global__ __launch_bounds__(384) void k_mlp(const float* __restrict__ xst,
                                             const float* __restrict__ qw,
                                             const float* __restrict__ dw,
                                             const float* __restrict__ fc1w,
                                             const float* __restrict__ fc1b,
                                             const float* __restrict__ fc2w,
                                             const float* __restrict__ fc2b,
                                             const float* __restrict__ po1,
                                             float* __restrict__ constv){
  int b = blockIdx.x, tid = threadIdx.x;
  __shared__ float xsl[432];
  __shared__ float lst[3456];
  __shared__ float avg[384];
  __shared__ float y1[24];
  __shared__ float Lb[384];
  for(int i=tid;i<432;i+=384) xsl[i] = xst[(size_t)b*432 + i];
  __syncthreads();
  {
    float st[9];
    #pragma unroll
    for(int s=0;s<9;s++) st[s]=0.f;
    const float* w = qw + (size_t)(1152+tid)*48;
    for(int c=0;c<48;c++){
      float wv = w[c];
      #pragma unroll
      for(int s=0;s<9;s++) st[s] += wv*xsl[c*9+s];
    }
    #pragma unroll
    for(int s=0;s<9;s++) lst[tid*9+s] = st[s];
  }
  __syncthreads();
  {
    int base = tid & ~7;
    const float* ls = &lst[base*9];
    float s = 0.f;
    #pragma unroll
    for(int i=0;i<8;i++){
      float T=ls[i*9+0],R0=ls[i*9+1],R1=ls[i*9+2],C0=ls[i*9+3],C1=ls[i*9+4];
      float c00=ls[i*9+5],c0W=ls[i*9+6],cH0=ls[i*9+7],cHW=ls[i*9+8];
      const float* wp = dw + (size_t)(1152+tid)*72 + i*9;
      #pragma unroll
      for(int dy=0;dy<3;dy++){
        float rm = (dy==0)?R1:((dy==2)?R0:0.f);
        #pragma unroll
        for(int dx=0;dx<3;dx++){
          float cm = (dx==0)?C1:((dx==2)?C0:0.f);
          float corner = 0.f;
          if(dy==0&&dx==0)corner=cHW;
          if(dy==0&&dx==2)corner=cH0;
          if(dy==2&&dx==0)corner=c0W;
          if(dy==2&&dx==2)corner=c00;
          s += wp[dy*3+dx]*(T-rm-cm+corner);
        }
      }
    }
    avg[tid] = s*(1.f/16384.f);
  }
  __syncthreads();
  if(tid<24){
    float s = fc1b[tid];
    const float* w = fc1w + (size_t)tid*384;
    for(int c=0;c<384;c++) s += w[c]*avg[c];
    y1[tid] = fmaxf(s,0.f);
  }
  __syncthreads();
  {
    float s = fc2b[tid];
    const float* w = fc2w + (size_t)tid*24;
    #pragma unroll
    for(int j=0;j<24;j++) s += w[j]*y1[j];
    Lb[tid] = s/(1.f+__expf(-s));
  }
  __syncthreads();
  if(tid<48){
    const float* w = po1 + (size_t)tid*384;
    float s = 0.f;
    for(int c=0;c<384;c++) s += w[c]*Lb[c];
    constv[b*48+tid] = s;
  }
}

// per (b,h): normalize, softmax, m2t[b][h*48+d][o] = sum_c po1[o][h*48+c]*attn[c][d]
__global__ __launch_bounds__(256) void k_attn(const float* __restrict__ Sred,
                                              const float* __restrict__ qn2,
                                              const float* __restrict__ temp,
                                              const float* __restrict__ po1,
                                              float* __restrict__ m2t){
  int h = blockIdx.x, b = blockIdx.y, tid = threadIdx.x;
  __shared__ float att[2304];
  __shared__ float nq[48], nk[48];
  const float* kn2 = qn2 + 1536;
  if(tid<48)      nq[tid]    = fmaxf(sqrtf(qn2[(size_t)b*D1 + h*48 + tid]),    1e-12f);
  else if(tid<96) nk[tid-48] = fmaxf(sqrtf(kn2[(size_t)b*D1 + h*48 + tid-48]), 1e-12f);
  __syncthreads();
  float tmp = temp[h];
  const float* Sp = Sred + (size_t)(b*HEADS+h)*2304;
  for(int idx=tid; idx<2304; idx+=256){
    int c = idx/48, d = idx - c*48;
    att[idx] = Sp[idx]*tmp/(nq[c]*nk[d]);
  }
  __syncthreads();
  if(tid<48){
    float* row = &att[tid*48];
    float m = -1e30f;
    for(int d=0;d<48;d++) m = fmaxf(m,row[d]);
    float s = 0.f;
    for(int d=0;d<48;d++){ float e=__expf(row[d]-m); row[d]=e; s+=e; }
    float inv = 1.f/s;
    for(int d=0;d<48;d++) row[d]*=inv;
  }
  __syncthreads();
  for(int idx=tid; idx<2304; idx+=256){
    int d = idx/48, o = idx - d*48;
    float s = 0.f;
    for(int c=0;c<48;c++) s += po1[(size_t)o*D1 + h*48 + c]*att[c*48+d];
    m2t[((size_t)b*D1 + h*48 + d)*48 + o] = s;
  }
}

// out[b][o][pos] = x + constv[o] + sum_hd m2t[b][hd][o]*v[b][hd][pos]
__global__ __launch_bounds__(256) void k_final(const ushort_t* __restrict__ qkvd,
                                               const float* __restrict__ m2t,
                                               const float* __restrict__ constv,
                                               const float* __restrict__ x,
                                               float* __restrict__ out){
  int tid = threadIdx.x;
  int pos = blockIdx.x*256 + tid;
  int b   = blockIdx.y;
  const ushort_t* vbase = qkvd + ((size_t)b*1152 + 768)*HW + pos;
  const float* m2 = m2t + (size_t)b*D1*48;
  float acc[48];
  #pragma unroll
  for(int o=0;o<48;o++) acc[o]=0.f;
  for(int ch=0;ch<384;ch+=8){
    float vv[8];
    #pragma unroll
    for(int j=0;j<8;j++) vv[j] = bf2f(vbase[(size_t)(ch+j)*HW]);
    #pragma unroll
    for(int j=0;j<8;j++){
      const float* mrow = m2 + (size_t)(ch+j)*48;
      #pragma unroll
      for(int o=0;o<48;o++) acc[o] += mrow[o]*vv[j];
    }
  }
  const float* xb = x   + (size_t)b*CC*HW + pos;
  float*       ob = out + (size_t)b*CC*HW + pos;
  const float* cv = constv + b*48;
  #pragma unroll
  for(int o=0;o<48;o++) ob[(size_t)o*HW] = xb[(size_t)o*HW] + cv[o] + acc[o];
}

extern "C" void kernel_launch(void* const* d_in, const int* in_sizes, int n_in,
                              void* d_out, int out_size, void* d_ws, size_t ws_size,
                              hipStream_t stream){
  const float* x    = (const float*)d_in[0];
  const float* qw   = (const float*)d_in[1];
  const float* dw   = (const float*)d_in[2];
  const float* po1  = (const float*)d_in[3];
  const float* fc1w = (const float*)d_in[4];
  const float* fc1b = (const float*)d_in[5];
  const float* fc2w = (const float*)d_in[6];
  const float* fc2b = (const float*)d_in[7];
  const float* temp = (const float*)d_in[8];
  float* out = (float*)d_out;
  char* ws = (char*)d_ws;

  // workspace layout (~162.1 MB)
  ushort_t* qkvd   = (ushort_t*)(ws);                 // 150,994,944
  float*    Spart  = (float*)(ws + 150994944);        // 9,437,184
  float*    qn2    = (float*)(ws + 160432128);        // 12,288 (qn2 + kn2)
  float*    xst    = (float*)(ws + 160444416);        // 6,912
  float*    constv = (float*)(ws + 160451328);        // 768
  float*    m2t    = (float*)(ws + 160452096);        // 294,912
  ushort_t* wfp    = (ushort_t*)(ws + 160747008);     // 1,032,192
  float*    Sred   = (float*)(ws + 161779200);        // 294,912

  k_zero  <<<dim3(12),           256, 0, stream>>>(qn2, 3072);
  k_wf    <<<dim3(1152),         256, 0, stream>>>(dw, qw, wfp);
  k_xstats<<<dim3(48,BB),        256, 0, stream>>>(x, xst);
  k_conv  <<<dim3(128,9,BB),     256, 0, stream>>>(x, wfp, qkvd);
  k_S     <<<dim3(32,HEADS,BB),  256, 0, stream>>>(qkvd, Spart, qn2);
  k_sred  <<<dim3(288),          256, 0, stream>>>(Spart, Sred);
  k_mlp   <<<dim3(BB),           384, 0, stream>>>(xst, qw, dw, fc1w, fc1b, fc2w, fc2b, po1, constv);
  k_attn  <<<dim3(HEADS,BB),     256, 0, stream>>>(Sred, qn2, temp, po1, m2t);
  k_final <<<dim3(64,BB),        256, 0, stream>>>(qkvd, m2t, constv, x, out);
}

// Round 6
// 426.275 us; speedup vs baseline: 4.3312x; 1.0520x over previous
//
#include <hip/hip_runtime.h>
#include <cstdint>

#define BB 4
#define CC 48
#define HW 16384
#define D1 384
#define HEADS 8

typedef unsigned short ushort_t;
typedef __attribute__((ext_vector_type(8))) short short8;
typedef __attribute__((ext_vector_type(4))) float f32x4;

__device__ __forceinline__ float bf2f(ushort_t u){
  union{uint32_t i; float f;} v; v.i = ((uint32_t)u)<<16; return v.f;
}
__device__ __forceinline__ ushort_t f2bf(float f){
  union{float f; uint32_t i;} v; v.f=f;
  uint32_t x = v.i;
  uint32_t r = (x + 0x7fff + ((x>>16)&1)) >> 16;
  return (ushort_t)r;
}

// fused-weight precompute + qn2 zeroing (blocks 0..11)
__global__ __launch_bounds__(256) void k_wf(const float* __restrict__ dw,
                                            const float* __restrict__ qw,
                                            ushort_t* __restrict__ wfp,
                                            float* __restrict__ qn2){
  int oc = blockIdx.x, tid = threadIdx.x;
  if(oc < 12){ int i = oc*256 + tid; if(i < 3072) qn2[i] = 0.f; }
  for(int kk=tid; kk<448; kk+=256){
    int t = kk/48, c = kk - t*48;
    float s = 0.f;
    if(t < 9){
      #pragma unroll
      for(int j=0;j<8;j++)
        s += dw[(size_t)oc*72 + j*9 + t] * qw[(size_t)((oc>>3)*8 + j)*48 + c];
    }
    wfp[(size_t)oc*448 + kk] = f2bf(s);
  }
}

// 9 boundary stats per (b, x-channel)
__global__ __launch_bounds__(256) void k_xstats(const float* __restrict__ x,
                                                float* __restrict__ xst){
  int ch = blockIdx.x, b = blockIdx.y;
  const float* p = x + ((size_t)b*CC + ch)*HW;
  int tid = threadIdx.x;
  float T=0,R0=0,R1=0,C0=0,C1=0;
  for(int i=tid;i<HW;i+=256){
    float v = p[i];
    T += v;
    if(i<128)      R0 += v;
    if(i>=16256)   R1 += v;
    int xc = i & 127;
    if(xc==0)      C0 += v;
    if(xc==127)    C1 += v;
  }
  __shared__ float red[20];
  for(int off=32;off;off>>=1){
    T  += __shfl_down(T,off);  R0 += __shfl_down(R0,off); R1 += __shfl_down(R1,off);
    C0 += __shfl_down(C0,off); C1 += __shfl_down(C1,off);
  }
  int wv = tid>>6, ln = tid&63;
  if(ln==0){ red[wv]=T; red[4+wv]=R0; red[8+wv]=R1; red[12+wv]=C0; red[16+wv]=C1; }
  __syncthreads();
  if(tid==0){
    float* o = xst + ((size_t)b*CC + ch)*9;
    o[0]=red[0]+red[1]+red[2]+red[3];
    o[1]=red[4]+red[5]+red[6]+red[7];
    o[2]=red[8]+red[9]+red[10]+red[11];
    o[3]=red[12]+red[13]+red[14]+red[15];
    o[4]=red[16]+red[17]+red[18]+red[19];
    o[5]=p[0]; o[6]=p[127]; o[7]=p[16256]; o[8]=p[16383];
  }
}

// dense 3x3 conv 48->1152 as MFMA GEMM; x staged ONCE, 9 oc-slices inside.
#define HROWC 64
__global__ __launch_bounds__(256,2) void k_conv(const float* __restrict__ x,
                                                const ushort_t* __restrict__ wfp,
                                                ushort_t* __restrict__ qkvd){
  __shared__ __align__(16) ushort_t xs[180*HROWC];   // 23040 B
  int tid  = threadIdx.x;
  int wave = tid>>6, lane = tid&63;
  int quad = lane>>4, mrow = lane&15;
  int mhalf = wave>>1, nhalf = wave&1;
  int tile = blockIdx.x;              // 128 tiles: 16 (y) x 8 (x)
  int ty0 = (tile>>3)*8, tx0 = (tile&7)*16;
  int b   = blockIdx.y;

  // ---- stage halo once: (g,r) unit = 8 strided loads -> one b128 LDS write ----
  const float* xb = x + (size_t)b*CC*HW;
  for(int u=tid; u<1080; u+=256){      // 6 groups * 180 rows
    int g = u/180, r = u - g*180;
    int hy = r/18, hx = r - hy*18;
    int gy = ty0+hy-1, gx = tx0+hx-1;
    bool in = ((unsigned)gy<128u) && ((unsigned)gx<128u);
    const float* bp = xb + (size_t)(g<<3)*HW + (gy*128+gx);
    ushort_t tmp[8];
    #pragma unroll
    for(int j=0;j<8;j++) tmp[j] = f2bf(in ? bp[(size_t)j*HW] : 0.f);
    *(short8*)(xs + r*HROWC + ((g ^ (r&7))<<3)) = *(short8*)tmp;
  }
  __syncthreads();

  int rb[4];
  #pragma unroll
  for(int nt=0;nt<4;nt++) rb[nt] = (nhalf*4+nt+1)*18 + mrow + 1;

  const ushort_t* Ab = wfp + (size_t)(mhalf*64 + mrow)*448 + quad*8;
  short8 Ac[4], An[4];
  #pragma unroll
  for(int mt=0;mt<4;mt++) Ac[mt] = *(const short8*)(Ab + (size_t)mt*16*448);

  for(int os=0; os<9; os++){
    const ushort_t* AbN = Ab + (size_t)128*448;
    f32x4 Cacc[4][4];
    #pragma unroll
    for(int mt=0;mt<4;mt++)
      #pragma unroll
      for(int nt=0;nt<4;nt++) Cacc[mt][nt] = (f32x4){0.f,0.f,0.f,0.f};

    #pragma unroll
    for(int chunk=0; chunk<14; chunk++){
      if(chunk < 13){
        #pragma unroll
        for(int mt=0;mt<4;mt++)
          An[mt] = *(const short8*)(Ab + (size_t)mt*16*448 + (chunk+1)*32);
      } else if(os < 8){
        #pragma unroll
        for(int mt=0;mt<4;mt++)
          An[mt] = *(const short8*)(AbN + (size_t)mt*16*448);
      }
      int kq = chunk*32 + quad*8;
      int t  = kq/48;
      int c  = kq - t*48;
      int tc = (t<9) ? t : 8;            // A is zero for t=9; B junk harmless
      int dyq = tc/3;
      int drow = dyq*18 + (tc - dyq*3) - 19;
      int g = c>>3;
      short8 Bf[4];
      #pragma unroll
      for(int nt=0;nt<4;nt++){
        int r = rb[nt] + drow;
        Bf[nt] = *(const short8*)(xs + r*HROWC + ((g ^ (r&7))<<3));
      }
      #pragma unroll
      for(int mt=0;mt<4;mt++)
        #pragma unroll
        for(int nt=0;nt<4;nt++)
          Cacc[mt][nt] = __builtin_amdgcn_mfma_f32_16x16x32_bf16(Ac[mt], Bf[nt], Cacc[mt][nt], 0,0,0);
      #pragma unroll
      for(int mt=0;mt<4;mt++) Ac[mt] = An[mt];
    }

    int ocb = os*128 + mhalf*64;
    #pragma unroll
    for(int mt=0;mt<4;mt++){
      #pragma unroll
      for(int nt=0;nt<4;nt++){
        int py = nhalf*4 + nt;
        int gpos = (ty0+py)*128 + tx0 + mrow;
        #pragma unroll
        for(int r=0;r<4;r++){
          int oc = ocb + mt*16 + quad*4 + r;
          qkvd[((size_t)b*1152 + oc)*HW + gpos] = f2bf(Cacc[mt][nt][r]);
        }
      }
    }
    Ab = AbN;
  }
}

// S = Q K^T per (b,h) via MFMA; norms free as diag(Q Q^T), diag(K K^T).
__global__ __launch_bounds__(256,3) void k_S(const ushort_t* __restrict__ qkvd,
                                             float* __restrict__ Spart,
                                             float* __restrict__ qn2){
  __shared__ __align__(16) ushort_t qk[96*264];   // 50688 B
  int tid = threadIdx.x;
  int blk = blockIdx.x, h = blockIdx.y, b = blockIdx.z;
  int wave = tid>>6, lane = tid&63;
  int quad = lane>>4, mrow = lane&15;
  const ushort_t* qb = qkvd + ((size_t)b*1152 + h*48)*HW;
  const ushort_t* kb = qb + (size_t)384*HW;

  f32x4 accS[3][3], accq[3], acck[3];
  #pragma unroll
  for(int mt=0;mt<3;mt++){
    accq[mt] = (f32x4){0.f,0.f,0.f,0.f};
    acck[mt] = (f32x4){0.f,0.f,0.f,0.f};
    #pragma unroll
    for(int nt=0;nt<3;nt++) accS[mt][nt] = (f32x4){0.f,0.f,0.f,0.f};
  }

  for(int half=0; half<2; half++){
    int p0 = blk*512 + half*256;
    __syncthreads();
    for(int u=tid; u<3072; u+=256){            // 96 ch x 32 b128-units
      int ch = u>>5, px = u&31;
      const ushort_t* src = ((ch<48) ? qb + (size_t)ch*HW
                                     : kb + (size_t)(ch-48)*HW) + p0 + px*8;
      *(short8*)(qk + ch*264 + px*8) = *(const short8*)src;
    }
    __syncthreads();
    #pragma unroll
    for(int ks=0; ks<2; ks++){
      int koff = wave*64 + ks*32 + quad*8;
      short8 Aq[3], Bk[3];
      #pragma unroll
      for(int mt=0;mt<3;mt++) Aq[mt] = *(const short8*)(qk + (mt*16+mrow)*264 + koff);
      #pragma unroll
      for(int nt=0;nt<3;nt++) Bk[nt] = *(const short8*)(qk + (48+nt*16+mrow)*264 + koff);
      #pragma unroll
      for(int mt=0;mt<3;mt++){
        accq[mt] = __builtin_amdgcn_mfma_f32_16x16x32_bf16(Aq[mt], Aq[mt], accq[mt], 0,0,0);
        acck[mt] = __builtin_amdgcn_mfma_f32_16x16x32_bf16(Bk[mt], Bk[mt], acck[mt], 0,0,0);
        #pragma unroll
        for(int nt=0;nt<3;nt++)
          accS[mt][nt] = __builtin_amdgcn_mfma_f32_16x16x32_bf16(Aq[mt], Bk[nt], accS[mt][nt], 0,0,0);
      }
    }
  }
  __syncthreads();
  float* scr = (float*)qk;
  #pragma unroll
  for(int mt=0;mt<3;mt++)
    #pragma unroll
    for(int nt=0;nt<3;nt++)
      #pragma unroll
      for(int r=0;r<4;r++)
        scr[wave*2304 + (mt*16+quad*4+r)*48 + nt*16 + mrow] = accS[mt][nt][r];
  __syncthreads();
  float* outp = Spart + ((size_t)((b*HEADS+h)*32 + blk))*2304;
  for(int idx=tid; idx<2304; idx+=256)
    outp[idx] = scr[idx] + scr[2304+idx] + scr[4608+idx] + scr[6912+idx];
  int rr = mrow - (quad<<2);
  #pragma unroll
  for(int r=0;r<4;r++){
    if(rr == r){
      #pragma unroll
      for(int mt=0;mt<3;mt++){
        atomicAdd(qn2 + (size_t)b*D1 + h*48 + mt*16 + mrow, accq[mt][r]);
        atomicAdd(qn2 + 1536 + (size_t)b*D1 + h*48 + mt*16 + mrow, acck[mt][r]);
      }
    }
  }
}

// per b: l-stats from x-stats -> mean -> fc1 -> relu -> fc2 -> swish -> constv = po1@L
__global__ __launch_bounds__(384) void k_mlp(const float* __restrict__ xst,
                                             const float* __restrict__ qw,
                                             const float* __restrict__ dw,
                                             const float* __restrict__ fc1w,
                                             const float* __restrict__ fc1b,
                                             const float* __restrict__ fc2w,
                                             const float* __restrict__ fc2b,
                                             const float* __restrict__ po1,
                                             float* __restrict__ constv){
  int b = blockIdx.x, tid = threadIdx.x;
  __shared__ float xsl[432];
  __shared__ float lst[3456];
  __shared__ float avg[384];
  __shared__ float y1[24];
  __shared__ float Lb[384];
  for(int i=tid;i<432;i+=384) xsl[i] = xst[(size_t)b*432 + i];
  __syncthreads();
  {
    float st[9];
    #pragma unroll
    for(int s=0;s<9;s++) st[s]=0.f;
    const float* w = qw + (size_t)(1152+tid)*48;
    for(int c=0;c<48;c++){
      float wv = w[c];
      #pragma unroll
      for(int s=0;s<9;s++) st[s] += wv*xsl[c*9+s];
    }
    #pragma unroll
    for(int s=0;s<9;s++) lst[tid*9+s] = st[s];
  }
  __syncthreads();
  {
    int base = tid & ~7;
    const float* ls = &lst[base*9];
    float s = 0.f;
    #pragma unroll
    for(int i=0;i<8;i++){
      float T=ls[i*9+0],R0=ls[i*9+1],R1=ls[i*9+2],C0=ls[i*9+3],C1=ls[i*9+4];
      float c00=ls[i*9+5],c0W=ls[i*9+6],cH0=ls[i*9+7],cHW=ls[i*9+8];
      const float* wp = dw + (size_t)(1152+tid)*72 + i*9;
      #pragma unroll
      for(int dy=0;dy<3;dy++){
        float rm = (dy==0)?R1:((dy==2)?R0:0.f);
        #pragma unroll
        for(int dx=0;dx<3;dx++){
          float cm = (dx==0)?C1:((dx==2)?C0:0.f);
          float corner = 0.f;
          if(dy==0&&dx==0)corner=cHW;
          if(dy==0&&dx==2)corner=cH0;
          if(dy==2&&dx==0)corner=c0W;
          if(dy==2&&dx==2)corner=c00;
          s += wp[dy*3+dx]*(T-rm-cm+corner);
        }
      }
    }
    avg[tid] = s*(1.f/16384.f);
  }
  __syncthreads();
  if(tid<24){
    float s = fc1b[tid];
    const float* w = fc1w + (size_t)tid*384;
    for(int c=0;c<384;c++) s += w[c]*avg[c];
    y1[tid] = fmaxf(s,0.f);
  }
  __syncthreads();
  {
    float s = fc2b[tid];
    const float* w = fc2w + (size_t)tid*24;
    #pragma unroll
    for(int j=0;j<24;j++) s += w[j]*y1[j];
    Lb[tid] = s/(1.f+__expf(-s));
  }
  __syncthreads();
  if(tid<48){
    const float* w = po1 + (size_t)tid*384;
    float s = 0.f;
    for(int c=0;c<384;c++) s += w[c]*Lb[c];
    constv[b*48+tid] = s;
  }
}

// per (b,h): sum Spart, normalize, softmax, m2o[b][o][h*48+d] (bf16) = sum_c po1[o][h*48+c]*attn[c][d]
__global__ __launch_bounds__(256) void k_attn(const float* __restrict__ Spart,
                                              const float* __restrict__ qn2,
                                              const float* __restrict__ temp,
                                              const float* __restrict__ po1,
                                              ushort_t* __restrict__ m2o){
  int h = blockIdx.x, b = blockIdx.y, tid = threadIdx.x;
  __shared__ float att[2304];
  __shared__ float nq[48], nk[48];
  const float* kn2 = qn2 + 1536;
  if(tid<48)      nq[tid]    = fmaxf(sqrtf(qn2[(size_t)b*D1 + h*48 + tid]),    1e-12f);
  else if(tid<96) nk[tid-48] = fmaxf(sqrtf(kn2[(size_t)b*D1 + h*48 + tid-48]), 1e-12f);
  __syncthreads();
  float tmp = temp[h];
  const float* Sp = Spart + ((size_t)(b*HEADS+h)*32)*2304;
  for(int idx=tid; idx<2304; idx+=256){
    float s = 0.f;
    for(int blk=0;blk<32;blk++) s += Sp[(size_t)blk*2304 + idx];
    int c = idx/48, d = idx - c*48;
    att[idx] = s*tmp/(nq[c]*nk[d]);
  }
  __syncthreads();
  if(tid<48){
    float* row = &att[tid*48];
    float m = -1e30f;
    for(int d=0;d<48;d++) m = fmaxf(m,row[d]);
    float s = 0.f;
    for(int d=0;d<48;d++){ float e=__expf(row[d]-m); row[d]=e; s+=e; }
    float inv = 1.f/s;
    for(int d=0;d<48;d++) row[d]*=inv;
  }
  __syncthreads();
  for(int idx=tid; idx<2304; idx+=256){
    int d = idx/48, o = idx - d*48;
    float s = 0.f;
    for(int c=0;c<48;c++) s += po1[(size_t)o*D1 + h*48 + c]*att[c*48+d];
    m2o[((size_t)b*48 + o)*D1 + h*48 + d] = f2bf(s);
  }
}

// out = x + constv + M2 @ V via MFMA; V transposed into LDS at staging.
#define FROW 40
__global__ __launch_bounds__(256) void k_final(const ushort_t* __restrict__ qkvd,
                                               const ushort_t* __restrict__ m2o,
                                               const float* __restrict__ constv,
                                               const float* __restrict__ x,
                                               float* __restrict__ out){
  __shared__ __align__(16) ushort_t vsT[256*FROW];   // 20480 B
  int tid = threadIdx.x;
  int wave = tid>>6, lane = tid&63;
  int quad = lane>>4, mrow = lane&15;
  int pos0 = blockIdx.x*256;
  int b = blockIdx.y;
  const ushort_t* vb = qkvd + ((size_t)b*1152 + 768)*HW + pos0;
  const ushort_t* Ab = m2o + (size_t)b*48*D1;
  f32x4 acc[3][4];
  #pragma unroll
  for(int mt=0;mt<3;mt++)
    #pragma unroll
    for(int nt=0;nt<4;nt++) acc[mt][nt] = (f32x4){0.f,0.f,0.f,0.f};
  int baddr[4];
  #pragma unroll
  for(int nt=0;nt<4;nt++){
    int p = wave*64 + nt*16 + mrow;
    baddr[nt] = p*FROW + ((quad ^ ((p>>3)&3))<<3);
  }
  for(int ck=0; ck<12; ck++){
    __syncthreads();
    {
      int p = tid;
      #pragma unroll
      for(int g=0; g<4; g++){
        const ushort_t* src = vb + (size_t)(ck*32 + g*8)*HW + p;
        ushort_t tmp[8];
        #pragma unroll
        for(int j=0;j<8;j++) tmp[j] = src[(size_t)j*HW];
        *(short8*)(vsT + p*FROW + ((g ^ ((p>>3)&3))<<3)) = *(short8*)tmp;
      }
    }
    __syncthreads();
    short8 Af[3], Bf[4];
    #pragma unroll
    for(int mt=0;mt<3;mt++)
      Af[mt] = *(const short8*)(Ab + (size_t)(mt*16+mrow)*D1 + ck*32 + quad*8);
    #pragma unroll
    for(int nt=0;nt<4;nt++) Bf[nt] = *(const short8*)(vsT + baddr[nt]);
    #pragma unroll
    for(int mt=0;mt<3;mt++)
      #pragma unroll
      for(int nt=0;nt<4;nt++)
        acc[mt][nt] = __builtin_amdgcn_mfma_f32_16x16x32_bf16(Af[mt], Bf[nt], acc[mt][nt], 0,0,0);
  }
  const float* xb = x + (size_t)b*CC*HW + pos0;
  float* ob = out + (size_t)b*CC*HW + pos0;
  #pragma unroll
  for(int mt=0;mt<3;mt++)
    #pragma unroll
    for(int nt=0;nt<4;nt++){
      int p = wave*64 + nt*16 + mrow;
      #pragma unroll
      for(int r=0;r<4;r++){
        int o = mt*16 + quad*4 + r;
        ob[(size_t)o*HW + p] = xb[(size_t)o*HW + p] + constv[b*48+o] + acc[mt][nt][r];
      }
    }
}

extern "C" void kernel_launch(void* const* d_in, const int* in_sizes, int n_in,
                              void* d_out, int out_size, void* d_ws, size_t ws_size,
                              hipStream_t stream){
  const float* x    = (const float*)d_in[0];
  const float* qw   = (const float*)d_in[1];
  const float* dw   = (const float*)d_in[2];
  const float* po1  = (const float*)d_in[3];
  const float* fc1w = (const float*)d_in[4];
  const float* fc1b = (const float*)d_in[5];
  const float* fc2w = (const float*)d_in[6];
  const float* fc2b = (const float*)d_in[7];
  const float* temp = (const float*)d_in[8];
  float* out = (float*)d_out;
  char* ws = (char*)d_ws;

  // workspace layout (~161.6 MB)
  ushort_t* qkvd   = (ushort_t*)(ws);                 // 150,994,944
  float*    Spart  = (float*)(ws + 150994944);        // 9,437,184
  float*    qn2    = (float*)(ws + 160432128);        // 12,288 (qn2 + kn2)
  float*    xst    = (float*)(ws + 160444416);        // 6,912
  float*    constv = (float*)(ws + 160451328);        // 768
  ushort_t* m2o    = (ushort_t*)(ws + 160452096);     // 147,456 (bf16 [b][48][384])
  ushort_t* wfp    = (ushort_t*)(ws + 160599552);     // 1,032,192

  k_wf    <<<dim3(1152),         256, 0, stream>>>(dw, qw, wfp, qn2);
  k_xstats<<<dim3(48,BB),        256, 0, stream>>>(x, xst);
  k_conv  <<<dim3(128,BB),       256, 0, stream>>>(x, wfp, qkvd);
  k_S     <<<dim3(32,HEADS,BB),  256, 0, stream>>>(qkvd, Spart, qn2);
  k_mlp   <<<dim3(BB),           384, 0, stream>>>(xst, qw, dw, fc1w, fc1b, fc2w, fc2b, po1, constv);
  k_attn  <<<dim3(HEADS,BB),     256, 0, stream>>>(Spart, qn2, temp, po1, m2o);
  k_final <<<dim3(64,BB),        256, 0, stream>>>(qkvd, m2o, constv, x, out);
}